// Round 1
// 809.799 us; speedup vs baseline: 1.0818x; 1.0818x over previous
//
#include <hip/hip_runtime.h>
#include <math.h>

#define N_NODES 100000
#define N_EDGES 1600000
#define M_TOT   (N_EDGES + N_NODES)   // edges + self loops = 1,700,000
#define C_DIM   128
#define NEG_SLOPE 0.2f
#define BN_EPS 1e-5f

#define NBUCK 8
#define BUCK_NODES 12500
#define BUCK_CAP 240000

#define KS2 72                        // LDS k-stride for 64-k split (8 pad)
#define BN_NB 256                     // bn_stats blocks
#define SCAN_NB 98                    // ceil(100000/1024)

typedef _Float16 f16x8 __attribute__((ext_vector_type(8)));
typedef float f32x4 __attribute__((ext_vector_type(4)));

static __device__ __forceinline__ unsigned short f2h(float f) {
    _Float16 h = (_Float16)f;
    unsigned short u;
    __builtin_memcpy(&u, &h, 2);
    return u;
}
static __device__ __forceinline__ float h2f(unsigned short u) {
    _Float16 h;
    __builtin_memcpy(&h, &u, 2);
    return (float)h;
}

// ---------------------------------------------------------------------------
// utility
// ---------------------------------------------------------------------------
__global__ void zero_i32(int* __restrict__ p, int n) {
    int i = blockIdx.x * blockDim.x + threadIdx.x;
    if (i < n) p[i] = 0;
}

// ---------------------------------------------------------------------------
// CSR build, XCD-partitioned bucket sort
// ---------------------------------------------------------------------------
__global__ __launch_bounds__(256) void bucket_edges(const int* __restrict__ ei,
                                                    int* __restrict__ bucket_next,
                                                    int2* __restrict__ buckets) {
    __shared__ int cnt[NBUCK];
    __shared__ int base[NBUCK];
    int tid = threadIdx.x;
    if (tid < NBUCK) cnt[tid] = 0;
    __syncthreads();
    int m = blockIdx.x * 256 + tid;
    int src = 0, dst = 0, p = 0, myoff = 0;
    bool valid = (m < M_TOT);
    if (valid) {
        if (m < N_EDGES) { src = ei[m]; dst = ei[N_EDGES + m]; }
        else             { src = m - N_EDGES; dst = src; }
        p = dst / BUCK_NODES;
        myoff = atomicAdd(&cnt[p], 1);
    }
    __syncthreads();
    if (tid < NBUCK) base[tid] = (cnt[tid] > 0) ? atomicAdd(&bucket_next[tid], cnt[tid]) : 0;
    __syncthreads();
    if (valid) {
        buckets[(size_t)p * BUCK_CAP + base[p] + myoff] = make_int2(src, dst);
    }
}

__global__ __launch_bounds__(256) void count_deg_b(const int2* __restrict__ buckets,
                                                   const int* __restrict__ bucket_next,
                                                   int* __restrict__ deg) {
    int p = blockIdx.x & 7;
    int chunk = blockIdx.x >> 3;
    int len = bucket_next[p];
    const int2* b = buckets + (size_t)p * BUCK_CAP;
    int stride = (gridDim.x >> 3) * 256;
    for (int i = chunk * 256 + threadIdx.x; i < len; i += stride) {
        atomicAdd(&deg[b[i].y], 1);
    }
}

__global__ __launch_bounds__(256) void scatter_b(const int2* __restrict__ buckets,
                                                 const int* __restrict__ bucket_next,
                                                 int* __restrict__ nextp,
                                                 int* __restrict__ csr_src) {
    int p = blockIdx.x & 7;
    int chunk = blockIdx.x >> 3;
    int len = bucket_next[p];
    const int2* b = buckets + (size_t)p * BUCK_CAP;
    int stride = (gridDim.x >> 3) * 256;
    for (int i = chunk * 256 + threadIdx.x; i < len; i += stride) {
        int2 e = b[i];
        int pos = atomicAdd(&nextp[e.y], 1);
        csr_src[pos] = e.x;
    }
}

// ---------------------------------------------------------------------------
// prefix scan over deg -> row_ptr / nextp (separate kernels: kernel-boundary
// visibility; no cross-XCD ticket races)
// ---------------------------------------------------------------------------
__global__ __launch_bounds__(256) void block_sums(const int* __restrict__ deg,
                                                  int* __restrict__ partials) {
    __shared__ int lds[256];
    int base = blockIdx.x * 1024;
    int s = 0;
    for (int i = threadIdx.x; i < 1024; i += 256) {
        int idx = base + i;
        if (idx < N_NODES) s += deg[idx];
    }
    lds[threadIdx.x] = s;
    __syncthreads();
    for (int off = 128; off > 0; off >>= 1) {
        if (threadIdx.x < off) lds[threadIdx.x] += lds[threadIdx.x + off];
        __syncthreads();
    }
    if (threadIdx.x == 0) partials[blockIdx.x] = lds[0];
}

__global__ __launch_bounds__(128) void scan_partials(int* __restrict__ partials, int nb,
                                                     int* __restrict__ row_ptr) {
    __shared__ int lds[128];
    int tid = threadIdx.x;
    int v = (tid < nb) ? partials[tid] : 0;
    lds[tid] = v;
    __syncthreads();
    for (int off = 1; off < 128; off <<= 1) {
        int t = (tid >= off) ? lds[tid - off] : 0;
        __syncthreads();
        lds[tid] += t;
        __syncthreads();
    }
    if (tid < nb) partials[tid] = lds[tid] - v;   // exclusive
    if (tid == 0) row_ptr[N_NODES] = M_TOT;
}

__global__ __launch_bounds__(256) void scan_write(const int* __restrict__ deg,
                                                  const int* __restrict__ partials,
                                                  int* __restrict__ row_ptr,
                                                  int* __restrict__ nextp) {
    __shared__ int lds[256];
    int tid = threadIdx.x;
    int base = blockIdx.x * 1024;
    int i0 = base + tid * 4;
    int d[4];
#pragma unroll
    for (int t = 0; t < 4; ++t)
        d[t] = (i0 + t < N_NODES) ? deg[i0 + t] : 0;
    int tsum = d[0] + d[1] + d[2] + d[3];
    lds[tid] = tsum;
    __syncthreads();
    for (int off = 1; off < 256; off <<= 1) {
        int v = (tid >= off) ? lds[tid - off] : 0;
        __syncthreads();
        lds[tid] += v;
        __syncthreads();
    }
    int excl = lds[tid] - tsum;
    int run = partials[blockIdx.x] + excl;
#pragma unroll
    for (int t = 0; t < 4; ++t) {
        if (i0 + t < N_NODES) {
            row_ptr[i0 + t] = run;
            nextp[i0 + t]   = run;
            run += d[t];
        }
    }
}

// ---------------------------------------------------------------------------
// MFMA fp16 GEMM, K-split staging: two 64-K stages, LDS 36.9 KB -> 3 blk/CU.
// Tile 128x128 per 256-thr block; mfma_f32_16x16x32_f16; fused Ssrc/Sdst.
// ---------------------------------------------------------------------------
__global__ __launch_bounds__(256, 3) void gemm_attn(
    const float* __restrict__ X, int ldx,
    const float* __restrict__ W,
    const float* __restrict__ a_src, const float* __restrict__ a_dst,
    unsigned short* __restrict__ Hh, float* __restrict__ Ssrc,
    float* __restrict__ Sdst) {
    __shared__ unsigned short Xs[128 * KS2];   // 18.4 KB
    __shared__ unsigned short Wt[128 * KS2];   // 18.4 KB
    int tid = threadIdx.x;
    int rbase = blockIdx.x * 128;

    int wave = tid >> 6;
    int lane = tid & 63;
    int q = lane >> 4;
    int l15 = lane & 15;
    int wrow = wave * 32;

    f32x4 acc[2][8] = {};

    for (int kb = 0; kb < 128; kb += 64) {
        __syncthreads();   // protect LDS reuse from previous stage's readers
        // stage X rows 0..127, k-cols kb..kb+63 (fp32->fp16)
        {
            int rl = tid >> 4;            // 0..15
            int cg = (tid & 15) * 4;      // 0,4,..,60
#pragma unroll
            for (int i = 0; i < 8; ++i) {
                int r = rl + i * 16;
                int row = rbase + r;
                if (row >= N_NODES) row = N_NODES - 1;
                float4 v = *(const float4*)&X[(size_t)row * ldx + kb + cg];
                ushort4 o;
                o.x = f2h(v.x); o.y = f2h(v.y); o.z = f2h(v.z); o.w = f2h(v.w);
                *(ushort4*)&Xs[r * KS2 + cg] = o;
            }
        }
        // stage W transposed: Wt[n][kk] = W[kb+kk][n]
        {
            int kl = tid >> 5;            // 0..7
            int n4 = (tid & 31) * 4;
#pragma unroll
            for (int i = 0; i < 8; ++i) {
                int kk = kl + i * 8;
                float4 v = *(const float4*)&W[(kb + kk) * 128 + n4];
                Wt[(n4 + 0) * KS2 + kk] = f2h(v.x);
                Wt[(n4 + 1) * KS2 + kk] = f2h(v.y);
                Wt[(n4 + 2) * KS2 + kk] = f2h(v.z);
                Wt[(n4 + 3) * KS2 + kk] = f2h(v.w);
            }
        }
        __syncthreads();
#pragma unroll
        for (int ks = 0; ks < 64; ks += 32) {
            int k0 = ks + q * 8;
            f16x8 a0 = *(f16x8*)&Xs[(wrow + l15) * KS2 + k0];
            f16x8 a1 = *(f16x8*)&Xs[(wrow + 16 + l15) * KS2 + k0];
#pragma unroll
            for (int c = 0; c < 8; ++c) {
                f16x8 b = *(f16x8*)&Wt[(c * 16 + l15) * KS2 + k0];
                acc[0][c] = __builtin_amdgcn_mfma_f32_16x16x32_f16(a0, b, acc[0][c], 0, 0, 0);
                acc[1][c] = __builtin_amdgcn_mfma_f32_16x16x32_f16(a1, b, acc[1][c], 0, 0, 0);
            }
        }
    }

    // epilogue: C/D layout col=lane&15, row=(lane>>4)*4+reg
    float avs[8], avd[8];
#pragma unroll
    for (int c = 0; c < 8; ++c) {
        avs[c] = a_src[c * 16 + l15];
        avd[c] = a_dst[c * 16 + l15];
    }
#pragma unroll
    for (int r = 0; r < 2; ++r) {
        float ps[4] = {0, 0, 0, 0}, pd[4] = {0, 0, 0, 0};
#pragma unroll
        for (int g = 0; g < 4; ++g) {
            int row = rbase + wrow + r * 16 + q * 4 + g;
            bool ok = (row < N_NODES);
#pragma unroll
            for (int c = 0; c < 8; ++c) {
                float h = acc[r][c][g];
                if (ok) Hh[(size_t)row * 128 + c * 16 + l15] = f2h(h);
                ps[g] = fmaf(h, avs[c], ps[g]);
                pd[g] = fmaf(h, avd[c], pd[g]);
            }
        }
#pragma unroll
        for (int g = 0; g < 4; ++g) {
#pragma unroll
            for (int off = 1; off < 16; off <<= 1) {
                ps[g] += __shfl_xor(ps[g], off, 64);
                pd[g] += __shfl_xor(pd[g], off, 64);
            }
        }
        if (l15 == 0) {
#pragma unroll
            for (int g = 0; g < 4; ++g) {
                int row = rbase + wrow + r * 16 + q * 4 + g;
                if (row < N_NODES) {
                    Ssrc[row] = ps[g];
                    Sdst[row] = pd[g];
                }
            }
        }
    }
}

// ---------------------------------------------------------------------------
// Per-node softmax + weighted aggregation.
// Softmax is shift-invariant: instead of a separate segment-max pass, anchor
// on the node's own self-loop score (always present). Scores are ~N(0,2) so
// exponents stay far below fp32 overflow (~88).
// 4 edges per wave: 16 lanes x f16x8 (16B) = full 256B row per edge slot;
// 2-deep unroll keeps two independent gather chains in flight.
// ---------------------------------------------------------------------------
__global__ __launch_bounds__(256) void aggregate(
    const unsigned short* __restrict__ Hh, const int* __restrict__ row_ptr,
    const int* __restrict__ csr_src,
    const float* __restrict__ Ssrc, const float* __restrict__ Sdst,
    const float* __restrict__ bias, float* __restrict__ Y) {
    int wave = threadIdx.x >> 6;
    int lane = threadIdx.x & 63;
    int g = lane >> 4;               // edge slot 0..3
    int l15 = lane & 15;             // channel group: ch = l15*8 + i
    int v = blockIdx.x * 4 + wave;
    int start = row_ptr[v];
    int end = row_ptr[v + 1];
    float sdv = Sdst[v];

    // anchor = self-loop score (exact softmax shift-invariance)
    float sself = Ssrc[v] + sdv;
    float m = (sself > 0.0f) ? sself : NEG_SLOPE * sself;

    float acc[8] = {0, 0, 0, 0, 0, 0, 0, 0};
    float denom = 0.0f;

    int j = start;
    for (; j + 8 <= end; j += 8) {
        int u0 = csr_src[j + g];
        int u1 = csr_src[j + 4 + g];
        float ss0 = Ssrc[u0];
        float ss1 = Ssrc[u1];
        f16x8 h0 = *(const f16x8*)&Hh[(size_t)u0 * 128 + l15 * 8];
        f16x8 h1 = *(const f16x8*)&Hh[(size_t)u1 * 128 + l15 * 8];
        float s0 = ss0 + sdv; s0 = (s0 > 0.0f) ? s0 : NEG_SLOPE * s0;
        float s1 = ss1 + sdv; s1 = (s1 > 0.0f) ? s1 : NEG_SLOPE * s1;
        float w0 = __expf(s0 - m);
        float w1 = __expf(s1 - m);
        denom += w0 + w1;
#pragma unroll
        for (int i = 0; i < 8; ++i) acc[i] = fmaf(w0, (float)h0[i], acc[i]);
#pragma unroll
        for (int i = 0; i < 8; ++i) acc[i] = fmaf(w1, (float)h1[i], acc[i]);
    }
    for (; j < end; j += 4) {
        int je = j + g;
        bool ok = (je < end);
        int u = ok ? csr_src[je] : v;
        float s = Ssrc[u] + sdv; s = (s > 0.0f) ? s : NEG_SLOPE * s;
        float w = ok ? __expf(s - m) : 0.0f;
        f16x8 h = *(const f16x8*)&Hh[(size_t)u * 128 + l15 * 8];
        denom += w;
#pragma unroll
        for (int i = 0; i < 8; ++i) acc[i] = fmaf(w, (float)h[i], acc[i]);
    }

    // combine the 4 edge slots (lane bits 4 and 5)
#pragma unroll
    for (int i = 0; i < 8; ++i) {
        acc[i] += __shfl_xor(acc[i], 16, 64);
        acc[i] += __shfl_xor(acc[i], 32, 64);
    }
    denom += __shfl_xor(denom, 16, 64);
    denom += __shfl_xor(denom, 32, 64);

    if (g == 0) {
        float inv = 1.0f / denom;
        float4 b0 = *(const float4*)&bias[l15 * 8];
        float4 b1 = *(const float4*)&bias[l15 * 8 + 4];
        float4 o0, o1;
        o0.x = fmaxf(fmaf(acc[0], inv, b0.x), 0.0f);
        o0.y = fmaxf(fmaf(acc[1], inv, b0.y), 0.0f);
        o0.z = fmaxf(fmaf(acc[2], inv, b0.z), 0.0f);
        o0.w = fmaxf(fmaf(acc[3], inv, b0.w), 0.0f);
        o1.x = fmaxf(fmaf(acc[4], inv, b1.x), 0.0f);
        o1.y = fmaxf(fmaf(acc[5], inv, b1.y), 0.0f);
        o1.z = fmaxf(fmaf(acc[6], inv, b1.z), 0.0f);
        o1.w = fmaxf(fmaf(acc[7], inv, b1.w), 0.0f);
        *(float4*)&Y[(size_t)v * 128 + l15 * 8] = o0;
        *(float4*)&Y[(size_t)v * 128 + l15 * 8 + 4] = o1;
    }
}

// ---------------------------------------------------------------------------
// BatchNorm: per-block partial sums (no atomics, no cross-block reads within
// a kernel); bn_finalize reads partials across a kernel boundary (coherent).
// ---------------------------------------------------------------------------
__global__ __launch_bounds__(256) void bn_stats(const float* __restrict__ Y,
                                                float* __restrict__ partial) {
    __shared__ float red[256 * 8];    // 8 KB
    int tid = threadIdx.x;
    int rowlane = tid >> 5;           // 0..7
    int cg = tid & 31;                // col-group of 4
    float4 s = make_float4(0, 0, 0, 0);
    float4 qq = make_float4(0, 0, 0, 0);
    for (int i = blockIdx.x * 8 + rowlane; i < N_NODES; i += BN_NB * 8) {
        float4 v = *(const float4*)&Y[(size_t)i * 128 + cg * 4];
        s.x += v.x; s.y += v.y; s.z += v.z; s.w += v.w;
        qq.x = fmaf(v.x, v.x, qq.x);
        qq.y = fmaf(v.y, v.y, qq.y);
        qq.z = fmaf(v.z, v.z, qq.z);
        qq.w = fmaf(v.w, v.w, qq.w);
    }
    float* r = &red[tid * 8];
    r[0] = s.x; r[1] = s.y; r[2] = s.z; r[3] = s.w;
    r[4] = qq.x; r[5] = qq.y; r[6] = qq.z; r[7] = qq.w;
    __syncthreads();
    for (int off = 4; off > 0; off >>= 1) {
        if (rowlane < off) {
            float* o = &red[(tid + off * 32) * 8];
#pragma unroll
            for (int t = 0; t < 8; ++t) r[t] += o[t];
        }
        __syncthreads();
    }
    if (rowlane == 0) {
        *(float4*)&partial[(size_t)blockIdx.x * 256 + cg * 4] =
            make_float4(r[0], r[1], r[2], r[3]);
        *(float4*)&partial[(size_t)blockIdx.x * 256 + 128 + cg * 4] =
            make_float4(r[4], r[5], r[6], r[7]);
    }
}

__global__ __launch_bounds__(256) void bn_finalize(const float* __restrict__ partial,
                                                   const float* __restrict__ gamma,
                                                   const float* __restrict__ beta,
                                                   float* __restrict__ gb) {
    __shared__ float tot[256];
    int tid = threadIdx.x;
    float acc = 0.0f;
    for (int b = 0; b < BN_NB; ++b) acc += partial[(size_t)b * 256 + tid];
    tot[tid] = acc;
    __syncthreads();
    if (tid < 128) {
        const float invN = 1.0f / (float)N_NODES;
        float mu = tot[tid] * invN;
        float var = tot[128 + tid] * invN - mu * mu;
        float g = gamma[tid] * rsqrtf(var + BN_EPS);
        gb[tid] = g;
        gb[128 + tid] = beta[tid] - mu * g;
    }
}

__global__ __launch_bounds__(256) void bn_apply(const float* __restrict__ Y,
                                                const float* __restrict__ gb,
                                                float* __restrict__ out) {
    int idx = blockIdx.x * blockDim.x + threadIdx.x;
    if (idx >= N_NODES * 32) return;
    int row = idx >> 5;
    int c4 = (idx & 31) * 4;
    float4 v = *(const float4*)&Y[(size_t)row * 128 + c4];
    float4 g = *(const float4*)&gb[c4];
    float4 b = *(const float4*)&gb[128 + c4];
    v.x = fmaf(v.x, g.x, b.x);
    v.y = fmaf(v.y, g.y, b.y);
    v.z = fmaf(v.z, g.z, b.z);
    v.w = fmaf(v.w, g.w, b.w);
    *(float4*)&out[(size_t)row * 384 + c4] = v;
}

// ---------------------------------------------------------------------------
// driver
// ---------------------------------------------------------------------------
extern "C" void kernel_launch(void* const* d_in, const int* in_sizes, int n_in,
                              void* d_out, int out_size, void* d_ws, size_t ws_size,
                              hipStream_t stream) {
    const float* x      = (const float*)d_in[0];
    const int*   ei     = (const int*)d_in[1];   // [2, E] int32
    const float* Wall   = (const float*)d_in[2];
    const float* asrcs  = (const float*)d_in[3];
    const float* adsts  = (const float*)d_in[4];
    const float* biases = (const float*)d_in[5];
    const float* gammas = (const float*)d_in[6];
    const float* betas  = (const float*)d_in[7];
    float* out = (float*)d_out;

    // workspace layout
    unsigned short* Hh = (unsigned short*)d_ws;              // N*128 fp16
    float* Y       = (float*)(Hh + (size_t)N_NODES * 128);   // N*128 fp32
    float* Ssrc    = Y + (size_t)N_NODES * 128;
    float* Sdst    = Ssrc + N_NODES;
    float* bnpart  = Sdst + N_NODES;                         // 256*256
    float* gb      = bnpart + BN_NB * 256;                   // 256
    // ---- zero zone (contiguous) ----
    int* deg       = (int*)(gb + 256);                       // 100000
    int* bucket_next = deg + N_NODES;                        // 8
    // ---- end zero zone ----
    int* row_ptr   = bucket_next + NBUCK;                    // 100001
    int* nextp     = row_ptr + (N_NODES + 1);                // 100000
    int* partials  = nextp + N_NODES;                        // 128
    int* csr_src   = partials + 128;                         // 1.7M
    int2* buckets  = (int2*)(csr_src + M_TOT + 2);           // 8*240000 int2

    const int ZERO_CNT = N_NODES + NBUCK;
    const int NB_EDGE = (M_TOT + 255) / 256;                 // 6641
    const int NB_PART = 2048;

    // ---- CSR build (bucketed) ----
    zero_i32<<<(ZERO_CNT + 255) / 256, 256, 0, stream>>>(deg, ZERO_CNT);
    bucket_edges<<<NB_EDGE, 256, 0, stream>>>(ei, bucket_next, buckets);
    count_deg_b<<<NB_PART, 256, 0, stream>>>(buckets, bucket_next, deg);
    block_sums<<<SCAN_NB, 256, 0, stream>>>(deg, partials);
    scan_partials<<<1, 128, 0, stream>>>(partials, SCAN_NB, row_ptr);
    scan_write<<<SCAN_NB, 256, 0, stream>>>(deg, partials, row_ptr, nextp);
    scatter_b<<<NB_PART, 256, 0, stream>>>(buckets, bucket_next, nextp, csr_src);

    // ---- 3 GAT layers ----
    for (int l = 0; l < 3; ++l) {
        const float* xin = (l == 0) ? x : (out + (size_t)(l - 1) * 128);
        int ldx = (l == 0) ? 128 : 384;
        gemm_attn<<<(N_NODES + 127) / 128, 256, 0, stream>>>(
            xin, ldx, Wall + (size_t)l * 128 * 128,
            asrcs + l * 128, adsts + l * 128, Hh, Ssrc, Sdst);
        aggregate<<<N_NODES / 4, 256, 0, stream>>>(
            Hh, row_ptr, csr_src, Ssrc, Sdst, biases + l * 128, Y);
        bn_stats<<<BN_NB, 256, 0, stream>>>(Y, bnpart);
        bn_finalize<<<1, 256, 0, stream>>>(bnpart, gammas + l * 128,
                                           betas + l * 128, gb);
        bn_apply<<<(N_NODES * 32 + 255) / 256, 256, 0, stream>>>(
            Y, gb, out + (size_t)l * 128);
    }
}

// Round 2
// 803.818 us; speedup vs baseline: 1.0899x; 1.0074x over previous
//
#include <hip/hip_runtime.h>
#include <math.h>

#define N_NODES 100000
#define N_EDGES 1600000
#define M_TOT   (N_EDGES + N_NODES)   // edges + self loops = 1,700,000
#define C_DIM   128
#define NEG_SLOPE 0.2f
#define BN_EPS 1e-5f

#define NBUCK 8
#define BUCK_NODES 12500
#define BUCK_CAP 240000

#define KS2 72                        // LDS k-stride for 64-k split (8 pad)
#define BN_NB 256                     // bn_stats blocks
#define SCAN_NB 98                    // ceil(100000/1024)

typedef _Float16 f16x8 __attribute__((ext_vector_type(8)));
typedef float f32x4 __attribute__((ext_vector_type(4)));

static __device__ __forceinline__ unsigned short f2h(float f) {
    _Float16 h = (_Float16)f;
    unsigned short u;
    __builtin_memcpy(&u, &h, 2);
    return u;
}
static __device__ __forceinline__ float h2f(unsigned short u) {
    _Float16 h;
    __builtin_memcpy(&h, &u, 2);
    return (float)h;
}

// ---------------------------------------------------------------------------
// utility
// ---------------------------------------------------------------------------
__global__ void zero_i32(int* __restrict__ p, int n) {
    int i = blockIdx.x * blockDim.x + threadIdx.x;
    if (i < n) p[i] = 0;
}

// ---------------------------------------------------------------------------
// CSR build, XCD-partitioned bucket sort
// ---------------------------------------------------------------------------
__global__ __launch_bounds__(256) void bucket_edges(const int* __restrict__ ei,
                                                    int* __restrict__ bucket_next,
                                                    int2* __restrict__ buckets) {
    __shared__ int cnt[NBUCK];
    __shared__ int base[NBUCK];
    int tid = threadIdx.x;
    if (tid < NBUCK) cnt[tid] = 0;
    __syncthreads();
    int m = blockIdx.x * 256 + tid;
    int src = 0, dst = 0, p = 0, myoff = 0;
    bool valid = (m < M_TOT);
    if (valid) {
        if (m < N_EDGES) { src = ei[m]; dst = ei[N_EDGES + m]; }
        else             { src = m - N_EDGES; dst = src; }
        p = dst / BUCK_NODES;
        myoff = atomicAdd(&cnt[p], 1);
    }
    __syncthreads();
    if (tid < NBUCK) base[tid] = (cnt[tid] > 0) ? atomicAdd(&bucket_next[tid], cnt[tid]) : 0;
    __syncthreads();
    if (valid) {
        buckets[(size_t)p * BUCK_CAP + base[p] + myoff] = make_int2(src, dst);
    }
}

__global__ __launch_bounds__(256) void count_deg_b(const int2* __restrict__ buckets,
                                                   const int* __restrict__ bucket_next,
                                                   int* __restrict__ deg) {
    int p = blockIdx.x & 7;
    int chunk = blockIdx.x >> 3;
    int len = bucket_next[p];
    const int2* b = buckets + (size_t)p * BUCK_CAP;
    int stride = (gridDim.x >> 3) * 256;
    for (int i = chunk * 256 + threadIdx.x; i < len; i += stride) {
        atomicAdd(&deg[b[i].y], 1);
    }
}

__global__ __launch_bounds__(256) void scatter_b(const int2* __restrict__ buckets,
                                                 const int* __restrict__ bucket_next,
                                                 int* __restrict__ nextp,
                                                 int* __restrict__ csr_src) {
    int p = blockIdx.x & 7;
    int chunk = blockIdx.x >> 3;
    int len = bucket_next[p];
    const int2* b = buckets + (size_t)p * BUCK_CAP;
    int stride = (gridDim.x >> 3) * 256;
    for (int i = chunk * 256 + threadIdx.x; i < len; i += stride) {
        int2 e = b[i];
        int pos = atomicAdd(&nextp[e.y], 1);
        csr_src[pos] = e.x;
    }
}

// ---------------------------------------------------------------------------
// prefix scan over deg -> row_ptr / nextp
// ---------------------------------------------------------------------------
__global__ __launch_bounds__(256) void block_sums(const int* __restrict__ deg,
                                                  int* __restrict__ partials) {
    __shared__ int lds[256];
    int base = blockIdx.x * 1024;
    int s = 0;
    for (int i = threadIdx.x; i < 1024; i += 256) {
        int idx = base + i;
        if (idx < N_NODES) s += deg[idx];
    }
    lds[threadIdx.x] = s;
    __syncthreads();
    for (int off = 128; off > 0; off >>= 1) {
        if (threadIdx.x < off) lds[threadIdx.x] += lds[threadIdx.x + off];
        __syncthreads();
    }
    if (threadIdx.x == 0) partials[blockIdx.x] = lds[0];
}

__global__ __launch_bounds__(128) void scan_partials(int* __restrict__ partials, int nb,
                                                     int* __restrict__ row_ptr) {
    __shared__ int lds[128];
    int tid = threadIdx.x;
    int v = (tid < nb) ? partials[tid] : 0;
    lds[tid] = v;
    __syncthreads();
    for (int off = 1; off < 128; off <<= 1) {
        int t = (tid >= off) ? lds[tid - off] : 0;
        __syncthreads();
        lds[tid] += t;
        __syncthreads();
    }
    if (tid < nb) partials[tid] = lds[tid] - v;   // exclusive
    if (tid == 0) row_ptr[N_NODES] = M_TOT;
}

__global__ __launch_bounds__(256) void scan_write(const int* __restrict__ deg,
                                                  const int* __restrict__ partials,
                                                  int* __restrict__ row_ptr,
                                                  int* __restrict__ nextp) {
    __shared__ int lds[256];
    int tid = threadIdx.x;
    int base = blockIdx.x * 1024;
    int i0 = base + tid * 4;
    int d[4];
#pragma unroll
    for (int t = 0; t < 4; ++t)
        d[t] = (i0 + t < N_NODES) ? deg[i0 + t] : 0;
    int tsum = d[0] + d[1] + d[2] + d[3];
    lds[tid] = tsum;
    __syncthreads();
    for (int off = 1; off < 256; off <<= 1) {
        int v = (tid >= off) ? lds[tid - off] : 0;
        __syncthreads();
        lds[tid] += v;
        __syncthreads();
    }
    int excl = lds[tid] - tsum;
    int run = partials[blockIdx.x] + excl;
#pragma unroll
    for (int t = 0; t < 4; ++t) {
        if (i0 + t < N_NODES) {
            row_ptr[i0 + t] = run;
            nextp[i0 + t]   = run;
            run += d[t];
        }
    }
}

// ---------------------------------------------------------------------------
// MFMA fp16 GEMM, K-split staging: two 64-K stages, LDS 36.9 KB -> 3 blk/CU.
// Tile 128x128 per 256-thr block; mfma_f32_16x16x32_f16; fused Ssrc/Sdst.
// For layers >=1 the BN "apply" of the previous layer is fused into staging:
// reads raw Y + gb, writes the normalized value to the out slice (bitwise
// identical to what bn_apply produced) and converts it to fp16 for the GEMM.
// ---------------------------------------------------------------------------
__global__ __launch_bounds__(256, 3) void gemm_attn(
    const float* __restrict__ X, int ldx,
    const float* __restrict__ W,
    const float* __restrict__ a_src, const float* __restrict__ a_dst,
    const float* __restrict__ gbv,           // nullptr for layer 0
    float* __restrict__ outw,                // out slice of previous layer
    unsigned short* __restrict__ Hh, float* __restrict__ Ssrc,
    float* __restrict__ Sdst) {
    __shared__ unsigned short Xs[128 * KS2];   // 18.4 KB
    __shared__ unsigned short Wt[128 * KS2];   // 18.4 KB
    int tid = threadIdx.x;
    int rbase = blockIdx.x * 128;

    int wave = tid >> 6;
    int lane = tid & 63;
    int q = lane >> 4;
    int l15 = lane & 15;
    int wrow = wave * 32;

    f32x4 acc[2][8] = {};

    for (int kb = 0; kb < 128; kb += 64) {
        __syncthreads();   // protect LDS reuse from previous stage's readers
        // stage X rows 0..127, k-cols kb..kb+63 (fp32->fp16), fused BN apply
        {
            int rl = tid >> 4;            // 0..15
            int cg = (tid & 15) * 4;      // 0,4,..,60
            float4 gg = make_float4(1.f, 1.f, 1.f, 1.f);
            float4 bb = make_float4(0.f, 0.f, 0.f, 0.f);
            if (gbv) {
                gg = *(const float4*)&gbv[kb + cg];
                bb = *(const float4*)&gbv[128 + kb + cg];
            }
#pragma unroll
            for (int i = 0; i < 8; ++i) {
                int r = rl + i * 16;
                int row0 = rbase + r;
                bool ok = (row0 < N_NODES);
                int row = ok ? row0 : (N_NODES - 1);
                float4 v = *(const float4*)&X[(size_t)row * ldx + kb + cg];
                if (gbv) {
                    v.x = fmaf(v.x, gg.x, bb.x);
                    v.y = fmaf(v.y, gg.y, bb.y);
                    v.z = fmaf(v.z, gg.z, bb.z);
                    v.w = fmaf(v.w, gg.w, bb.w);
                    if (ok) *(float4*)&outw[(size_t)row * 384 + kb + cg] = v;
                }
                ushort4 o;
                o.x = f2h(v.x); o.y = f2h(v.y); o.z = f2h(v.z); o.w = f2h(v.w);
                *(ushort4*)&Xs[r * KS2 + cg] = o;
            }
        }
        // stage W transposed: Wt[n][kk] = W[kb+kk][n]
        {
            int kl = tid >> 5;            // 0..7
            int n4 = (tid & 31) * 4;
#pragma unroll
            for (int i = 0; i < 8; ++i) {
                int kk = kl + i * 8;
                float4 v = *(const float4*)&W[(kb + kk) * 128 + n4];
                Wt[(n4 + 0) * KS2 + kk] = f2h(v.x);
                Wt[(n4 + 1) * KS2 + kk] = f2h(v.y);
                Wt[(n4 + 2) * KS2 + kk] = f2h(v.z);
                Wt[(n4 + 3) * KS2 + kk] = f2h(v.w);
            }
        }
        __syncthreads();
#pragma unroll
        for (int ks = 0; ks < 64; ks += 32) {
            int k0 = ks + q * 8;
            f16x8 a0 = *(f16x8*)&Xs[(wrow + l15) * KS2 + k0];
            f16x8 a1 = *(f16x8*)&Xs[(wrow + 16 + l15) * KS2 + k0];
#pragma unroll
            for (int c = 0; c < 8; ++c) {
                f16x8 b = *(f16x8*)&Wt[(c * 16 + l15) * KS2 + k0];
                acc[0][c] = __builtin_amdgcn_mfma_f32_16x16x32_f16(a0, b, acc[0][c], 0, 0, 0);
                acc[1][c] = __builtin_amdgcn_mfma_f32_16x16x32_f16(a1, b, acc[1][c], 0, 0, 0);
            }
        }
    }

    // epilogue: C/D layout col=lane&15, row=(lane>>4)*4+reg
    float avs[8], avd[8];
#pragma unroll
    for (int c = 0; c < 8; ++c) {
        avs[c] = a_src[c * 16 + l15];
        avd[c] = a_dst[c * 16 + l15];
    }
#pragma unroll
    for (int r = 0; r < 2; ++r) {
        float ps[4] = {0, 0, 0, 0}, pd[4] = {0, 0, 0, 0};
#pragma unroll
        for (int g = 0; g < 4; ++g) {
            int row = rbase + wrow + r * 16 + q * 4 + g;
            bool ok = (row < N_NODES);
#pragma unroll
            for (int c = 0; c < 8; ++c) {
                float h = acc[r][c][g];
                if (ok) Hh[(size_t)row * 128 + c * 16 + l15] = f2h(h);
                ps[g] = fmaf(h, avs[c], ps[g]);
                pd[g] = fmaf(h, avd[c], pd[g]);
            }
        }
#pragma unroll
        for (int g = 0; g < 4; ++g) {
#pragma unroll
            for (int off = 1; off < 16; off <<= 1) {
                ps[g] += __shfl_xor(ps[g], off, 64);
                pd[g] += __shfl_xor(pd[g], off, 64);
            }
        }
        if (l15 == 0) {
#pragma unroll
            for (int g = 0; g < 4; ++g) {
                int row = rbase + wrow + r * 16 + q * 4 + g;
                if (row < N_NODES) {
                    Ssrc[row] = ps[g];
                    Sdst[row] = pd[g];
                }
            }
        }
    }
}

// ---------------------------------------------------------------------------
// Per-node softmax + weighted aggregation.
// Self-loop score as softmax anchor (exact via shift-invariance).
// 4 edges per wave (16 lanes x f16x8 = full 256B row per edge slot);
// 4-deep chain unroll (16 edges/iter) for memory-level parallelism.
// ---------------------------------------------------------------------------
__global__ __launch_bounds__(256) void aggregate(
    const unsigned short* __restrict__ Hh, const int* __restrict__ row_ptr,
    const int* __restrict__ csr_src,
    const float* __restrict__ Ssrc, const float* __restrict__ Sdst,
    const float* __restrict__ bias, float* __restrict__ Y) {
    int wave = threadIdx.x >> 6;
    int lane = threadIdx.x & 63;
    int g = lane >> 4;               // edge slot 0..3
    int l15 = lane & 15;             // channel group: ch = l15*8 + i
    int v = blockIdx.x * 4 + wave;
    int start = row_ptr[v];
    int end = row_ptr[v + 1];
    float sdv = Sdst[v];

    // anchor = self-loop score (exact softmax shift-invariance)
    float sself = Ssrc[v] + sdv;
    float m = (sself > 0.0f) ? sself : NEG_SLOPE * sself;

    float acc[8] = {0, 0, 0, 0, 0, 0, 0, 0};
    float denom = 0.0f;

    int j = start;
    for (; j + 16 <= end; j += 16) {
        int u0 = csr_src[j + g];
        int u1 = csr_src[j + 4 + g];
        int u2 = csr_src[j + 8 + g];
        int u3 = csr_src[j + 12 + g];
        float ss0 = Ssrc[u0];
        float ss1 = Ssrc[u1];
        float ss2 = Ssrc[u2];
        float ss3 = Ssrc[u3];
        f16x8 h0 = *(const f16x8*)&Hh[(size_t)u0 * 128 + l15 * 8];
        f16x8 h1 = *(const f16x8*)&Hh[(size_t)u1 * 128 + l15 * 8];
        f16x8 h2 = *(const f16x8*)&Hh[(size_t)u2 * 128 + l15 * 8];
        f16x8 h3 = *(const f16x8*)&Hh[(size_t)u3 * 128 + l15 * 8];
        float s0 = ss0 + sdv; s0 = (s0 > 0.0f) ? s0 : NEG_SLOPE * s0;
        float s1 = ss1 + sdv; s1 = (s1 > 0.0f) ? s1 : NEG_SLOPE * s1;
        float s2 = ss2 + sdv; s2 = (s2 > 0.0f) ? s2 : NEG_SLOPE * s2;
        float s3 = ss3 + sdv; s3 = (s3 > 0.0f) ? s3 : NEG_SLOPE * s3;
        float w0 = __expf(s0 - m);
        float w1 = __expf(s1 - m);
        float w2 = __expf(s2 - m);
        float w3 = __expf(s3 - m);
        denom += (w0 + w1) + (w2 + w3);
#pragma unroll
        for (int i = 0; i < 8; ++i) acc[i] = fmaf(w0, (float)h0[i], acc[i]);
#pragma unroll
        for (int i = 0; i < 8; ++i) acc[i] = fmaf(w1, (float)h1[i], acc[i]);
#pragma unroll
        for (int i = 0; i < 8; ++i) acc[i] = fmaf(w2, (float)h2[i], acc[i]);
#pragma unroll
        for (int i = 0; i < 8; ++i) acc[i] = fmaf(w3, (float)h3[i], acc[i]);
    }
    for (; j + 8 <= end; j += 8) {
        int u0 = csr_src[j + g];
        int u1 = csr_src[j + 4 + g];
        float ss0 = Ssrc[u0];
        float ss1 = Ssrc[u1];
        f16x8 h0 = *(const f16x8*)&Hh[(size_t)u0 * 128 + l15 * 8];
        f16x8 h1 = *(const f16x8*)&Hh[(size_t)u1 * 128 + l15 * 8];
        float s0 = ss0 + sdv; s0 = (s0 > 0.0f) ? s0 : NEG_SLOPE * s0;
        float s1 = ss1 + sdv; s1 = (s1 > 0.0f) ? s1 : NEG_SLOPE * s1;
        float w0 = __expf(s0 - m);
        float w1 = __expf(s1 - m);
        denom += w0 + w1;
#pragma unroll
        for (int i = 0; i < 8; ++i) acc[i] = fmaf(w0, (float)h0[i], acc[i]);
#pragma unroll
        for (int i = 0; i < 8; ++i) acc[i] = fmaf(w1, (float)h1[i], acc[i]);
    }
    for (; j < end; j += 4) {
        int je = j + g;
        bool ok = (je < end);
        int u = ok ? csr_src[je] : v;
        float s = Ssrc[u] + sdv; s = (s > 0.0f) ? s : NEG_SLOPE * s;
        float w = ok ? __expf(s - m) : 0.0f;
        f16x8 h = *(const f16x8*)&Hh[(size_t)u * 128 + l15 * 8];
        denom += w;
#pragma unroll
        for (int i = 0; i < 8; ++i) acc[i] = fmaf(w, (float)h[i], acc[i]);
    }

    // combine the 4 edge slots (lane bits 4 and 5)
#pragma unroll
    for (int i = 0; i < 8; ++i) {
        acc[i] += __shfl_xor(acc[i], 16, 64);
        acc[i] += __shfl_xor(acc[i], 32, 64);
    }
    denom += __shfl_xor(denom, 16, 64);
    denom += __shfl_xor(denom, 32, 64);

    if (g == 0) {
        float inv = 1.0f / denom;
        float4 b0 = *(const float4*)&bias[l15 * 8];
        float4 b1 = *(const float4*)&bias[l15 * 8 + 4];
        float4 o0, o1;
        o0.x = fmaxf(fmaf(acc[0], inv, b0.x), 0.0f);
        o0.y = fmaxf(fmaf(acc[1], inv, b0.y), 0.0f);
        o0.z = fmaxf(fmaf(acc[2], inv, b0.z), 0.0f);
        o0.w = fmaxf(fmaf(acc[3], inv, b0.w), 0.0f);
        o1.x = fmaxf(fmaf(acc[4], inv, b1.x), 0.0f);
        o1.y = fmaxf(fmaf(acc[5], inv, b1.y), 0.0f);
        o1.z = fmaxf(fmaf(acc[6], inv, b1.z), 0.0f);
        o1.w = fmaxf(fmaf(acc[7], inv, b1.w), 0.0f);
        *(float4*)&Y[(size_t)v * 128 + l15 * 8] = o0;
        *(float4*)&Y[(size_t)v * 128 + l15 * 8 + 4] = o1;
    }
}

// ---------------------------------------------------------------------------
// BatchNorm stats / finalize / apply (apply only used for the last layer;
// layers 0-1 are applied inside the next gemm_attn's staging).
// ---------------------------------------------------------------------------
__global__ __launch_bounds__(256) void bn_stats(const float* __restrict__ Y,
                                                float* __restrict__ partial) {
    __shared__ float red[256 * 8];    // 8 KB
    int tid = threadIdx.x;
    int rowlane = tid >> 5;           // 0..7
    int cg = tid & 31;                // col-group of 4
    float4 s = make_float4(0, 0, 0, 0);
    float4 qq = make_float4(0, 0, 0, 0);
    for (int i = blockIdx.x * 8 + rowlane; i < N_NODES; i += BN_NB * 8) {
        float4 v = *(const float4*)&Y[(size_t)i * 128 + cg * 4];
        s.x += v.x; s.y += v.y; s.z += v.z; s.w += v.w;
        qq.x = fmaf(v.x, v.x, qq.x);
        qq.y = fmaf(v.y, v.y, qq.y);
        qq.z = fmaf(v.z, v.z, qq.z);
        qq.w = fmaf(v.w, v.w, qq.w);
    }
    float* r = &red[tid * 8];
    r[0] = s.x; r[1] = s.y; r[2] = s.z; r[3] = s.w;
    r[4] = qq.x; r[5] = qq.y; r[6] = qq.z; r[7] = qq.w;
    __syncthreads();
    for (int off = 4; off > 0; off >>= 1) {
        if (rowlane < off) {
            float* o = &red[(tid + off * 32) * 8];
#pragma unroll
            for (int t = 0; t < 8; ++t) r[t] += o[t];
        }
        __syncthreads();
    }
    if (rowlane == 0) {
        *(float4*)&partial[(size_t)blockIdx.x * 256 + cg * 4] =
            make_float4(r[0], r[1], r[2], r[3]);
        *(float4*)&partial[(size_t)blockIdx.x * 256 + 128 + cg * 4] =
            make_float4(r[4], r[5], r[6], r[7]);
    }
}

__global__ __launch_bounds__(256) void bn_finalize(const float* __restrict__ partial,
                                                   const float* __restrict__ gamma,
                                                   const float* __restrict__ beta,
                                                   float* __restrict__ gb) {
    __shared__ float tot[256];
    int tid = threadIdx.x;
    float acc = 0.0f;
    for (int b = 0; b < BN_NB; ++b) acc += partial[(size_t)b * 256 + tid];
    tot[tid] = acc;
    __syncthreads();
    if (tid < 128) {
        const float invN = 1.0f / (float)N_NODES;
        float mu = tot[tid] * invN;
        float var = tot[128 + tid] * invN - mu * mu;
        float g = gamma[tid] * rsqrtf(var + BN_EPS);
        gb[tid] = g;
        gb[128 + tid] = beta[tid] - mu * g;
    }
}

__global__ __launch_bounds__(256) void bn_apply(const float* __restrict__ Y,
                                                const float* __restrict__ gb,
                                                float* __restrict__ out) {
    int idx = blockIdx.x * blockDim.x + threadIdx.x;
    if (idx >= N_NODES * 32) return;
    int row = idx >> 5;
    int c4 = (idx & 31) * 4;
    float4 v = *(const float4*)&Y[(size_t)row * 128 + c4];
    float4 g = *(const float4*)&gb[c4];
    float4 b = *(const float4*)&gb[128 + c4];
    v.x = fmaf(v.x, g.x, b.x);
    v.y = fmaf(v.y, g.y, b.y);
    v.z = fmaf(v.z, g.z, b.z);
    v.w = fmaf(v.w, g.w, b.w);
    *(float4*)&out[(size_t)row * 384 + c4] = v;
}

// ---------------------------------------------------------------------------
// driver
// ---------------------------------------------------------------------------
extern "C" void kernel_launch(void* const* d_in, const int* in_sizes, int n_in,
                              void* d_out, int out_size, void* d_ws, size_t ws_size,
                              hipStream_t stream) {
    const float* x      = (const float*)d_in[0];
    const int*   ei     = (const int*)d_in[1];   // [2, E] int32
    const float* Wall   = (const float*)d_in[2];
    const float* asrcs  = (const float*)d_in[3];
    const float* adsts  = (const float*)d_in[4];
    const float* biases = (const float*)d_in[5];
    const float* gammas = (const float*)d_in[6];
    const float* betas  = (const float*)d_in[7];
    float* out = (float*)d_out;

    // workspace layout
    unsigned short* Hh = (unsigned short*)d_ws;              // N*128 fp16
    float* Y       = (float*)(Hh + (size_t)N_NODES * 128);   // N*128 fp32
    float* Ssrc    = Y + (size_t)N_NODES * 128;
    float* Sdst    = Ssrc + N_NODES;
    float* bnpart  = Sdst + N_NODES;                         // 256*256
    float* gb      = bnpart + BN_NB * 256;                   // 256
    // ---- zero zone (contiguous) ----
    int* deg       = (int*)(gb + 256);                       // 100000
    int* bucket_next = deg + N_NODES;                        // 8
    // ---- end zero zone ----
    int* row_ptr   = bucket_next + NBUCK;                    // 100001
    int* nextp     = row_ptr + (N_NODES + 1);                // 100000
    int* partials  = nextp + N_NODES;                        // 128
    int* csr_src   = partials + 128;                         // 1.7M
    int2* buckets  = (int2*)(csr_src + M_TOT + 2);           // 8*240000 int2

    const int ZERO_CNT = N_NODES + NBUCK;
    const int NB_EDGE = (M_TOT + 255) / 256;                 // 6641
    const int NB_PART = 2048;

    // ---- CSR build (bucketed) ----
    zero_i32<<<(ZERO_CNT + 255) / 256, 256, 0, stream>>>(deg, ZERO_CNT);
    bucket_edges<<<NB_EDGE, 256, 0, stream>>>(ei, bucket_next, buckets);
    count_deg_b<<<NB_PART, 256, 0, stream>>>(buckets, bucket_next, deg);
    block_sums<<<SCAN_NB, 256, 0, stream>>>(deg, partials);
    scan_partials<<<1, 128, 0, stream>>>(partials, SCAN_NB, row_ptr);
    scan_write<<<SCAN_NB, 256, 0, stream>>>(deg, partials, row_ptr, nextp);
    scatter_b<<<NB_PART, 256, 0, stream>>>(buckets, bucket_next, nextp, csr_src);

    // ---- 3 GAT layers (BN apply of layer l-1 fused into gemm of layer l) ----
    for (int l = 0; l < 3; ++l) {
        const float* xin;
        int ldx;
        const float* gbl;
        float* outw;
        if (l == 0) { xin = x; ldx = 128; gbl = nullptr; outw = nullptr; }
        else        { xin = Y; ldx = 128; gbl = gb; outw = out + (size_t)(l - 1) * 128; }
        gemm_attn<<<(N_NODES + 127) / 128, 256, 0, stream>>>(
            xin, ldx, Wall + (size_t)l * 128 * 128,
            asrcs + l * 128, adsts + l * 128, gbl, outw, Hh, Ssrc, Sdst);
        aggregate<<<N_NODES / 4, 256, 0, stream>>>(
            Hh, row_ptr, csr_src, Ssrc, Sdst, biases + l * 128, Y);
        bn_stats<<<BN_NB, 256, 0, stream>>>(Y, bnpart);
        bn_finalize<<<1, 256, 0, stream>>>(bnpart, gammas + l * 128,
                                           betas + l * 128, gb);
    }
    // final layer's BN apply (no following gemm to fuse into)
    bn_apply<<<(N_NODES * 32 + 255) / 256, 256, 0, stream>>>(
        Y, gb, out + (size_t)2 * 128);
}

// Round 3
// 792.818 us; speedup vs baseline: 1.1050x; 1.0139x over previous
//
#include <hip/hip_runtime.h>
#include <math.h>

#define N_NODES 100000
#define N_EDGES 1600000
#define M_TOT   (N_EDGES + N_NODES)   // edges + self loops = 1,700,000
#define C_DIM   128
#define NEG_SLOPE 0.2f
#define BN_EPS 1e-5f

#define NBUCK 8
#define BUCK_NODES 12500
#define BUCK_CAP 240000

#define BN_NB 256                     // bn_stats blocks
#define SCAN_NB 98                    // ceil(100000/1024)

typedef _Float16 f16x8 __attribute__((ext_vector_type(8)));
typedef float f32x4 __attribute__((ext_vector_type(4)));

static __device__ __forceinline__ unsigned short f2h(float f) {
    _Float16 h = (_Float16)f;
    unsigned short u;
    __builtin_memcpy(&u, &h, 2);
    return u;
}
static __device__ __forceinline__ float h2f(unsigned short u) {
    _Float16 h;
    __builtin_memcpy(&h, &u, 2);
    return (float)h;
}
static __device__ __forceinline__ _Float16 f2h16(float f) { return (_Float16)f; }

// ---------------------------------------------------------------------------
// utility
// ---------------------------------------------------------------------------
__global__ void zero_i32(int* __restrict__ p, int n) {
    int i = blockIdx.x * blockDim.x + threadIdx.x;
    if (i < n) p[i] = 0;
}

// One-shot: convert all 3 W matrices to fp16, transposed to n-major:
// Wh[l][n][k] = (fp16) W[l][k][n].  32KB per layer -> L1-resident in gemm.
__global__ __launch_bounds__(256) void conv_w(const float* __restrict__ Wall,
                                              unsigned short* __restrict__ Wh) {
    int i = blockIdx.x * 256 + threadIdx.x;   // coalesced read index
    if (i >= 3 * 128 * 128) return;
    int l = i >> 14;
    int r = i & 16383;
    int k = r >> 7;
    int n = r & 127;
    Wh[(size_t)l * 16384 + n * 128 + k] = f2h(Wall[i]);
}

// ---------------------------------------------------------------------------
// CSR build, XCD-partitioned bucket sort
// ---------------------------------------------------------------------------
__global__ __launch_bounds__(256) void bucket_edges(const int* __restrict__ ei,
                                                    int* __restrict__ bucket_next,
                                                    int2* __restrict__ buckets) {
    __shared__ int cnt[NBUCK];
    __shared__ int base[NBUCK];
    int tid = threadIdx.x;
    if (tid < NBUCK) cnt[tid] = 0;
    __syncthreads();
    int m = blockIdx.x * 256 + tid;
    int src = 0, dst = 0, p = 0, myoff = 0;
    bool valid = (m < M_TOT);
    if (valid) {
        if (m < N_EDGES) { src = ei[m]; dst = ei[N_EDGES + m]; }
        else             { src = m - N_EDGES; dst = src; }
        p = dst / BUCK_NODES;
        myoff = atomicAdd(&cnt[p], 1);
    }
    __syncthreads();
    if (tid < NBUCK) base[tid] = (cnt[tid] > 0) ? atomicAdd(&bucket_next[tid], cnt[tid]) : 0;
    __syncthreads();
    if (valid) {
        buckets[(size_t)p * BUCK_CAP + base[p] + myoff] = make_int2(src, dst);
    }
}

__global__ __launch_bounds__(256) void count_deg_b(const int2* __restrict__ buckets,
                                                   const int* __restrict__ bucket_next,
                                                   int* __restrict__ deg) {
    int p = blockIdx.x & 7;
    int chunk = blockIdx.x >> 3;
    int len = bucket_next[p];
    const int2* b = buckets + (size_t)p * BUCK_CAP;
    int stride = (gridDim.x >> 3) * 256;
    for (int i = chunk * 256 + threadIdx.x; i < len; i += stride) {
        atomicAdd(&deg[b[i].y], 1);
    }
}

__global__ __launch_bounds__(256) void scatter_b(const int2* __restrict__ buckets,
                                                 const int* __restrict__ bucket_next,
                                                 int* __restrict__ nextp,
                                                 int* __restrict__ csr_src) {
    int p = blockIdx.x & 7;
    int chunk = blockIdx.x >> 3;
    int len = bucket_next[p];
    const int2* b = buckets + (size_t)p * BUCK_CAP;
    int stride = (gridDim.x >> 3) * 256;
    for (int i = chunk * 256 + threadIdx.x; i < len; i += stride) {
        int2 e = b[i];
        int pos = atomicAdd(&nextp[e.y], 1);
        csr_src[pos] = e.x;
    }
}

// ---------------------------------------------------------------------------
// prefix scan over deg -> row_ptr / nextp
// ---------------------------------------------------------------------------
__global__ __launch_bounds__(256) void block_sums(const int* __restrict__ deg,
                                                  int* __restrict__ partials) {
    __shared__ int lds[256];
    int base = blockIdx.x * 1024;
    int s = 0;
    for (int i = threadIdx.x; i < 1024; i += 256) {
        int idx = base + i;
        if (idx < N_NODES) s += deg[idx];
    }
    lds[threadIdx.x] = s;
    __syncthreads();
    for (int off = 128; off > 0; off >>= 1) {
        if (threadIdx.x < off) lds[threadIdx.x] += lds[threadIdx.x + off];
        __syncthreads();
    }
    if (threadIdx.x == 0) partials[blockIdx.x] = lds[0];
}

__global__ __launch_bounds__(128) void scan_partials(int* __restrict__ partials, int nb,
                                                     int* __restrict__ row_ptr) {
    __shared__ int lds[128];
    int tid = threadIdx.x;
    int v = (tid < nb) ? partials[tid] : 0;
    lds[tid] = v;
    __syncthreads();
    for (int off = 1; off < 128; off <<= 1) {
        int t = (tid >= off) ? lds[tid - off] : 0;
        __syncthreads();
        lds[tid] += t;
        __syncthreads();
    }
    if (tid < nb) partials[tid] = lds[tid] - v;   // exclusive
    if (tid == 0) row_ptr[N_NODES] = M_TOT;
}

__global__ __launch_bounds__(256) void scan_write(const int* __restrict__ deg,
                                                  const int* __restrict__ partials,
                                                  int* __restrict__ row_ptr,
                                                  int* __restrict__ nextp) {
    __shared__ int lds[256];
    int tid = threadIdx.x;
    int base = blockIdx.x * 1024;
    int i0 = base + tid * 4;
    int d[4];
#pragma unroll
    for (int t = 0; t < 4; ++t)
        d[t] = (i0 + t < N_NODES) ? deg[i0 + t] : 0;
    int tsum = d[0] + d[1] + d[2] + d[3];
    lds[tid] = tsum;
    __syncthreads();
    for (int off = 1; off < 256; off <<= 1) {
        int v = (tid >= off) ? lds[tid - off] : 0;
        __syncthreads();
        lds[tid] += v;
        __syncthreads();
    }
    int excl = lds[tid] - tsum;
    int run = partials[blockIdx.x] + excl;
#pragma unroll
    for (int t = 0; t < 4; ++t) {
        if (i0 + t < N_NODES) {
            row_ptr[i0 + t] = run;
            nextp[i0 + t]   = run;
            run += d[t];
        }
    }
}

// ---------------------------------------------------------------------------
// LDS-free MFMA fp16 GEMM. W pre-converted/transposed to fp16 (Wh[n][k],
// 32KB, L1-resident). A fragments loaded directly from global (each element
// exactly once, 128B-chunk coalesced), converted in-register. For layers >=1
// the previous layer's BN apply is fused into the A load (and the normalized
// value is stored to the out slice). No LDS, no barriers.
// ---------------------------------------------------------------------------
__global__ __launch_bounds__(256, 2) void gemm_attn(
    const float* __restrict__ X, int ldx,
    const unsigned short* __restrict__ Wh,
    const float* __restrict__ a_src, const float* __restrict__ a_dst,
    const float* __restrict__ gbv,           // nullptr for layer 0
    float* __restrict__ outw,                // out slice of previous layer
    unsigned short* __restrict__ Hh, float* __restrict__ Ssrc,
    float* __restrict__ Sdst) {
    int tid = threadIdx.x;
    int wave = tid >> 6;
    int lane = tid & 63;
    int q = lane >> 4;
    int l15 = lane & 15;
    int wrow = wave * 32;
    int rbase = blockIdx.x * 128;

    int row0 = rbase + wrow + l15;        // a0 rows
    int row1 = row0 + 16;                 // a1 rows
    bool ok0 = row0 < N_NODES, ok1 = row1 < N_NODES;
    int r0c = ok0 ? row0 : (N_NODES - 1);
    int r1c = ok1 ? row1 : (N_NODES - 1);

    f32x4 acc[2][8] = {};

#pragma unroll
    for (int ks = 0; ks < 128; ks += 32) {
        int k0 = ks + q * 8;
        float4 v0 = *(const float4*)&X[(size_t)r0c * ldx + k0];
        float4 v1 = *(const float4*)&X[(size_t)r0c * ldx + k0 + 4];
        float4 u0 = *(const float4*)&X[(size_t)r1c * ldx + k0];
        float4 u1 = *(const float4*)&X[(size_t)r1c * ldx + k0 + 4];
        if (gbv) {
            float4 g0 = *(const float4*)&gbv[k0];
            float4 g1 = *(const float4*)&gbv[k0 + 4];
            float4 b0 = *(const float4*)&gbv[128 + k0];
            float4 b1 = *(const float4*)&gbv[128 + k0 + 4];
            v0.x = fmaf(v0.x, g0.x, b0.x); v0.y = fmaf(v0.y, g0.y, b0.y);
            v0.z = fmaf(v0.z, g0.z, b0.z); v0.w = fmaf(v0.w, g0.w, b0.w);
            v1.x = fmaf(v1.x, g1.x, b1.x); v1.y = fmaf(v1.y, g1.y, b1.y);
            v1.z = fmaf(v1.z, g1.z, b1.z); v1.w = fmaf(v1.w, g1.w, b1.w);
            u0.x = fmaf(u0.x, g0.x, b0.x); u0.y = fmaf(u0.y, g0.y, b0.y);
            u0.z = fmaf(u0.z, g0.z, b0.z); u0.w = fmaf(u0.w, g0.w, b0.w);
            u1.x = fmaf(u1.x, g1.x, b1.x); u1.y = fmaf(u1.y, g1.y, b1.y);
            u1.z = fmaf(u1.z, g1.z, b1.z); u1.w = fmaf(u1.w, g1.w, b1.w);
            if (ok0) {
                *(float4*)&outw[(size_t)row0 * 384 + k0] = v0;
                *(float4*)&outw[(size_t)row0 * 384 + k0 + 4] = v1;
            }
            if (ok1) {
                *(float4*)&outw[(size_t)row1 * 384 + k0] = u0;
                *(float4*)&outw[(size_t)row1 * 384 + k0 + 4] = u1;
            }
        }
        f16x8 a0, a1;
        a0[0] = f2h16(v0.x); a0[1] = f2h16(v0.y); a0[2] = f2h16(v0.z); a0[3] = f2h16(v0.w);
        a0[4] = f2h16(v1.x); a0[5] = f2h16(v1.y); a0[6] = f2h16(v1.z); a0[7] = f2h16(v1.w);
        a1[0] = f2h16(u0.x); a1[1] = f2h16(u0.y); a1[2] = f2h16(u0.z); a1[3] = f2h16(u0.w);
        a1[4] = f2h16(u1.x); a1[5] = f2h16(u1.y); a1[6] = f2h16(u1.z); a1[7] = f2h16(u1.w);
#pragma unroll
        for (int c = 0; c < 8; ++c) {
            f16x8 b = *(const f16x8*)&Wh[(size_t)(c * 16 + l15) * 128 + k0];
            acc[0][c] = __builtin_amdgcn_mfma_f32_16x16x32_f16(a0, b, acc[0][c], 0, 0, 0);
            acc[1][c] = __builtin_amdgcn_mfma_f32_16x16x32_f16(a1, b, acc[1][c], 0, 0, 0);
        }
    }

    // epilogue: C/D layout col=lane&15, row=(lane>>4)*4+reg
    float avs[8], avd[8];
#pragma unroll
    for (int c = 0; c < 8; ++c) {
        avs[c] = a_src[c * 16 + l15];
        avd[c] = a_dst[c * 16 + l15];
    }
#pragma unroll
    for (int r = 0; r < 2; ++r) {
        float ps[4] = {0, 0, 0, 0}, pd[4] = {0, 0, 0, 0};
#pragma unroll
        for (int g = 0; g < 4; ++g) {
            int row = rbase + wrow + r * 16 + q * 4 + g;
            bool ok = (row < N_NODES);
#pragma unroll
            for (int c = 0; c < 8; ++c) {
                float h = acc[r][c][g];
                if (ok) Hh[(size_t)row * 128 + c * 16 + l15] = f2h(h);
                ps[g] = fmaf(h, avs[c], ps[g]);
                pd[g] = fmaf(h, avd[c], pd[g]);
            }
        }
#pragma unroll
        for (int g = 0; g < 4; ++g) {
#pragma unroll
            for (int off = 1; off < 16; off <<= 1) {
                ps[g] += __shfl_xor(ps[g], off, 64);
                pd[g] += __shfl_xor(pd[g], off, 64);
            }
        }
        if (l15 == 0) {
#pragma unroll
            for (int g = 0; g < 4; ++g) {
                int row = rbase + wrow + r * 16 + q * 4 + g;
                if (row < N_NODES) {
                    Ssrc[row] = ps[g];
                    Sdst[row] = pd[g];
                }
            }
        }
    }
}

// ---------------------------------------------------------------------------
// Per-node softmax + weighted aggregation.
// Self-loop score as softmax anchor (exact via shift-invariance).
// 4 edges per wave (16 lanes x f16x8 = full 256B row per edge slot);
// 4-deep chain unroll (16 edges/iter) for memory-level parallelism.
// ---------------------------------------------------------------------------
__global__ __launch_bounds__(256) void aggregate(
    const unsigned short* __restrict__ Hh, const int* __restrict__ row_ptr,
    const int* __restrict__ csr_src,
    const float* __restrict__ Ssrc, const float* __restrict__ Sdst,
    const float* __restrict__ bias, float* __restrict__ Y) {
    int wave = threadIdx.x >> 6;
    int lane = threadIdx.x & 63;
    int g = lane >> 4;               // edge slot 0..3
    int l15 = lane & 15;             // channel group: ch = l15*8 + i
    int v = blockIdx.x * 4 + wave;
    int start = row_ptr[v];
    int end = row_ptr[v + 1];
    float sdv = Sdst[v];

    // anchor = self-loop score (exact softmax shift-invariance)
    float sself = Ssrc[v] + sdv;
    float m = (sself > 0.0f) ? sself : NEG_SLOPE * sself;

    float acc[8] = {0, 0, 0, 0, 0, 0, 0, 0};
    float denom = 0.0f;

    int j = start;
    for (; j + 16 <= end; j += 16) {
        int u0 = csr_src[j + g];
        int u1 = csr_src[j + 4 + g];
        int u2 = csr_src[j + 8 + g];
        int u3 = csr_src[j + 12 + g];
        float ss0 = Ssrc[u0];
        float ss1 = Ssrc[u1];
        float ss2 = Ssrc[u2];
        float ss3 = Ssrc[u3];
        f16x8 h0 = *(const f16x8*)&Hh[(size_t)u0 * 128 + l15 * 8];
        f16x8 h1 = *(const f16x8*)&Hh[(size_t)u1 * 128 + l15 * 8];
        f16x8 h2 = *(const f16x8*)&Hh[(size_t)u2 * 128 + l15 * 8];
        f16x8 h3 = *(const f16x8*)&Hh[(size_t)u3 * 128 + l15 * 8];
        float s0 = ss0 + sdv; s0 = (s0 > 0.0f) ? s0 : NEG_SLOPE * s0;
        float s1 = ss1 + sdv; s1 = (s1 > 0.0f) ? s1 : NEG_SLOPE * s1;
        float s2 = ss2 + sdv; s2 = (s2 > 0.0f) ? s2 : NEG_SLOPE * s2;
        float s3 = ss3 + sdv; s3 = (s3 > 0.0f) ? s3 : NEG_SLOPE * s3;
        float w0 = __expf(s0 - m);
        float w1 = __expf(s1 - m);
        float w2 = __expf(s2 - m);
        float w3 = __expf(s3 - m);
        denom += (w0 + w1) + (w2 + w3);
#pragma unroll
        for (int i = 0; i < 8; ++i) acc[i] = fmaf(w0, (float)h0[i], acc[i]);
#pragma unroll
        for (int i = 0; i < 8; ++i) acc[i] = fmaf(w1, (float)h1[i], acc[i]);
#pragma unroll
        for (int i = 0; i < 8; ++i) acc[i] = fmaf(w2, (float)h2[i], acc[i]);
#pragma unroll
        for (int i = 0; i < 8; ++i) acc[i] = fmaf(w3, (float)h3[i], acc[i]);
    }
    for (; j + 8 <= end; j += 8) {
        int u0 = csr_src[j + g];
        int u1 = csr_src[j + 4 + g];
        float ss0 = Ssrc[u0];
        float ss1 = Ssrc[u1];
        f16x8 h0 = *(const f16x8*)&Hh[(size_t)u0 * 128 + l15 * 8];
        f16x8 h1 = *(const f16x8*)&Hh[(size_t)u1 * 128 + l15 * 8];
        float s0 = ss0 + sdv; s0 = (s0 > 0.0f) ? s0 : NEG_SLOPE * s0;
        float s1 = ss1 + sdv; s1 = (s1 > 0.0f) ? s1 : NEG_SLOPE * s1;
        float w0 = __expf(s0 - m);
        float w1 = __expf(s1 - m);
        denom += w0 + w1;
#pragma unroll
        for (int i = 0; i < 8; ++i) acc[i] = fmaf(w0, (float)h0[i], acc[i]);
#pragma unroll
        for (int i = 0; i < 8; ++i) acc[i] = fmaf(w1, (float)h1[i], acc[i]);
    }
    for (; j < end; j += 4) {
        int je = j + g;
        bool ok = (je < end);
        int u = ok ? csr_src[je] : v;
        float s = Ssrc[u] + sdv; s = (s > 0.0f) ? s : NEG_SLOPE * s;
        float w = ok ? __expf(s - m) : 0.0f;
        f16x8 h = *(const f16x8*)&Hh[(size_t)u * 128 + l15 * 8];
        denom += w;
#pragma unroll
        for (int i = 0; i < 8; ++i) acc[i] = fmaf(w, (float)h[i], acc[i]);
    }

    // combine the 4 edge slots (lane bits 4 and 5)
#pragma unroll
    for (int i = 0; i < 8; ++i) {
        acc[i] += __shfl_xor(acc[i], 16, 64);
        acc[i] += __shfl_xor(acc[i], 32, 64);
    }
    denom += __shfl_xor(denom, 16, 64);
    denom += __shfl_xor(denom, 32, 64);

    if (g == 0) {
        float inv = 1.0f / denom;
        float4 b0 = *(const float4*)&bias[l15 * 8];
        float4 b1 = *(const float4*)&bias[l15 * 8 + 4];
        float4 o0, o1;
        o0.x = fmaxf(fmaf(acc[0], inv, b0.x), 0.0f);
        o0.y = fmaxf(fmaf(acc[1], inv, b0.y), 0.0f);
        o0.z = fmaxf(fmaf(acc[2], inv, b0.z), 0.0f);
        o0.w = fmaxf(fmaf(acc[3], inv, b0.w), 0.0f);
        o1.x = fmaxf(fmaf(acc[4], inv, b1.x), 0.0f);
        o1.y = fmaxf(fmaf(acc[5], inv, b1.y), 0.0f);
        o1.z = fmaxf(fmaf(acc[6], inv, b1.z), 0.0f);
        o1.w = fmaxf(fmaf(acc[7], inv, b1.w), 0.0f);
        *(float4*)&Y[(size_t)v * 128 + l15 * 8] = o0;
        *(float4*)&Y[(size_t)v * 128 + l15 * 8 + 4] = o1;
    }
}

// ---------------------------------------------------------------------------
// BatchNorm stats / finalize / apply (apply only used for the last layer;
// layers 0-1 are applied inside the next gemm_attn's A-load).
// ---------------------------------------------------------------------------
__global__ __launch_bounds__(256) void bn_stats(const float* __restrict__ Y,
                                                float* __restrict__ partial) {
    __shared__ float red[256 * 8];    // 8 KB
    int tid = threadIdx.x;
    int rowlane = tid >> 5;           // 0..7
    int cg = tid & 31;                // col-group of 4
    float4 s = make_float4(0, 0, 0, 0);
    float4 qq = make_float4(0, 0, 0, 0);
    for (int i = blockIdx.x * 8 + rowlane; i < N_NODES; i += BN_NB * 8) {
        float4 v = *(const float4*)&Y[(size_t)i * 128 + cg * 4];
        s.x += v.x; s.y += v.y; s.z += v.z; s.w += v.w;
        qq.x = fmaf(v.x, v.x, qq.x);
        qq.y = fmaf(v.y, v.y, qq.y);
        qq.z = fmaf(v.z, v.z, qq.z);
        qq.w = fmaf(v.w, v.w, qq.w);
    }
    float* r = &red[tid * 8];
    r[0] = s.x; r[1] = s.y; r[2] = s.z; r[3] = s.w;
    r[4] = qq.x; r[5] = qq.y; r[6] = qq.z; r[7] = qq.w;
    __syncthreads();
    for (int off = 4; off > 0; off >>= 1) {
        if (rowlane < off) {
            float* o = &red[(tid + off * 32) * 8];
#pragma unroll
            for (int t = 0; t < 8; ++t) r[t] += o[t];
        }
        __syncthreads();
    }
    if (rowlane == 0) {
        *(float4*)&partial[(size_t)blockIdx.x * 256 + cg * 4] =
            make_float4(r[0], r[1], r[2], r[3]);
        *(float4*)&partial[(size_t)blockIdx.x * 256 + 128 + cg * 4] =
            make_float4(r[4], r[5], r[6], r[7]);
    }
}

__global__ __launch_bounds__(256) void bn_finalize(const float* __restrict__ partial,
                                                   const float* __restrict__ gamma,
                                                   const float* __restrict__ beta,
                                                   float* __restrict__ gb) {
    __shared__ float tot[256];
    int tid = threadIdx.x;
    float acc = 0.0f;
    for (int b = 0; b < BN_NB; ++b) acc += partial[(size_t)b * 256 + tid];
    tot[tid] = acc;
    __syncthreads();
    if (tid < 128) {
        const float invN = 1.0f / (float)N_NODES;
        float mu = tot[tid] * invN;
        float var = tot[128 + tid] * invN - mu * mu;
        float g = gamma[tid] * rsqrtf(var + BN_EPS);
        gb[tid] = g;
        gb[128 + tid] = beta[tid] - mu * g;
    }
}

__global__ __launch_bounds__(256) void bn_apply(const float* __restrict__ Y,
                                                const float* __restrict__ gb,
                                                float* __restrict__ out) {
    int idx = blockIdx.x * blockDim.x + threadIdx.x;
    if (idx >= N_NODES * 32) return;
    int row = idx >> 5;
    int c4 = (idx & 31) * 4;
    float4 v = *(const float4*)&Y[(size_t)row * 128 + c4];
    float4 g = *(const float4*)&gb[c4];
    float4 b = *(const float4*)&gb[128 + c4];
    v.x = fmaf(v.x, g.x, b.x);
    v.y = fmaf(v.y, g.y, b.y);
    v.z = fmaf(v.z, g.z, b.z);
    v.w = fmaf(v.w, g.w, b.w);
    *(float4*)&out[(size_t)row * 384 + c4] = v;
}

// ---------------------------------------------------------------------------
// driver
// ---------------------------------------------------------------------------
extern "C" void kernel_launch(void* const* d_in, const int* in_sizes, int n_in,
                              void* d_out, int out_size, void* d_ws, size_t ws_size,
                              hipStream_t stream) {
    const float* x      = (const float*)d_in[0];
    const int*   ei     = (const int*)d_in[1];   // [2, E] int32
    const float* Wall   = (const float*)d_in[2];
    const float* asrcs  = (const float*)d_in[3];
    const float* adsts  = (const float*)d_in[4];
    const float* biases = (const float*)d_in[5];
    const float* gammas = (const float*)d_in[6];
    const float* betas  = (const float*)d_in[7];
    float* out = (float*)d_out;

    // workspace layout
    unsigned short* Hh = (unsigned short*)d_ws;              // N*128 fp16
    float* Y       = (float*)(Hh + (size_t)N_NODES * 128);   // N*128 fp32
    float* Ssrc    = Y + (size_t)N_NODES * 128;
    float* Sdst    = Ssrc + N_NODES;
    float* bnpart  = Sdst + N_NODES;                         // 256*256
    float* gb      = bnpart + BN_NB * 256;                   // 256
    unsigned short* Wh = (unsigned short*)(gb + 256);        // 3*128*128 fp16 (16B aligned)
    // ---- zero zone (contiguous) ----
    int* deg       = (int*)(Wh + 3 * 128 * 128);             // 100000
    int* bucket_next = deg + N_NODES;                        // 8
    // ---- end zero zone ----
    int* row_ptr   = bucket_next + NBUCK;                    // 100001
    int* nextp     = row_ptr + (N_NODES + 1);                // 100000
    int* partials  = nextp + N_NODES;                        // 128
    int* csr_src   = partials + 128;                         // 1.7M
    int2* buckets  = (int2*)(csr_src + M_TOT + 2);           // 8*240000 int2

    const int ZERO_CNT = N_NODES + NBUCK;
    const int NB_EDGE = (M_TOT + 255) / 256;                 // 6641
    const int NB_PART = 2048;

    // ---- CSR build (bucketed) + one-shot W convert ----
    zero_i32<<<(ZERO_CNT + 255) / 256, 256, 0, stream>>>(deg, ZERO_CNT);
    conv_w<<<192, 256, 0, stream>>>(Wall, Wh);
    bucket_edges<<<NB_EDGE, 256, 0, stream>>>(ei, bucket_next, buckets);
    count_deg_b<<<NB_PART, 256, 0, stream>>>(buckets, bucket_next, deg);
    block_sums<<<SCAN_NB, 256, 0, stream>>>(deg, partials);
    scan_partials<<<1, 128, 0, stream>>>(partials, SCAN_NB, row_ptr);
    scan_write<<<SCAN_NB, 256, 0, stream>>>(deg, partials, row_ptr, nextp);
    scatter_b<<<NB_PART, 256, 0, stream>>>(buckets, bucket_next, nextp, csr_src);

    // ---- 3 GAT layers (BN apply of layer l-1 fused into gemm of layer l) ----
    for (int l = 0; l < 3; ++l) {
        const float* xin;
        int ldx;
        const float* gbl;
        float* outw;
        if (l == 0) { xin = x; ldx = 128; gbl = nullptr; outw = nullptr; }
        else        { xin = Y; ldx = 128; gbl = gb; outw = out + (size_t)(l - 1) * 128; }
        gemm_attn<<<(N_NODES + 127) / 128, 256, 0, stream>>>(
            xin, ldx, Wh + (size_t)l * 128 * 128,
            asrcs + l * 128, adsts + l * 128, gbl, outw, Hh, Ssrc, Sdst);
        aggregate<<<N_NODES / 4, 256, 0, stream>>>(
            Hh, row_ptr, csr_src, Ssrc, Sdst, biases + l * 128, Y);
        bn_stats<<<BN_NB, 256, 0, stream>>>(Y, bnpart);
        bn_finalize<<<1, 256, 0, stream>>>(bnpart, gammas + l * 128,
                                           betas + l * 128, gb);
    }
    // final layer's BN apply (no following gemm to fuse into)
    bn_apply<<<(N_NODES * 32 + 255) / 256, 256, 0, stream>>>(
        Y, gb, out + (size_t)2 * 128);
}

// Round 5
// 767.145 us; speedup vs baseline: 1.1420x; 1.0335x over previous
//
#include <hip/hip_runtime.h>
#include <math.h>

#define N_NODES 100000
#define N_EDGES 1600000
#define M_TOT   (N_EDGES + N_NODES)   // edges + self loops = 1,700,000
#define C_DIM   128
#define NEG_SLOPE 0.2f
#define BN_EPS 1e-5f

#define NBUCK 8
#define BUCK_NODES 12500
#define BUCK_CAP 240000

#define BN_NB 256                     // bn_stats blocks
#define SCAN_NB 98                    // ceil(100000/1024)
#define HS_LD 136                     // LDS halves stride (272B, 16B-aligned)

typedef _Float16 f16x8 __attribute__((ext_vector_type(8)));
typedef float f32x4 __attribute__((ext_vector_type(4)));

static __device__ __forceinline__ unsigned short f2h(float f) {
    _Float16 h = (_Float16)f;
    unsigned short u;
    __builtin_memcpy(&u, &h, 2);
    return u;
}
static __device__ __forceinline__ float h2f(unsigned short u) {
    _Float16 h;
    __builtin_memcpy(&h, &u, 2);
    return (float)h;
}
static __device__ __forceinline__ _Float16 f2h16(float f) { return (_Float16)f; }

// ---------------------------------------------------------------------------
// utility
// ---------------------------------------------------------------------------
__global__ void zero_i32(int* __restrict__ p, int n) {
    int i = blockIdx.x * blockDim.x + threadIdx.x;
    if (i < n) p[i] = 0;
}

// One-shot: convert all 3 W matrices to fp16, transposed to n-major:
// Wh[l][n][k] = (fp16) W[l][k][n].  32KB per layer -> L1/L2-resident in gemm.
__global__ __launch_bounds__(256) void conv_w(const float* __restrict__ Wall,
                                              unsigned short* __restrict__ Wh) {
    int i = blockIdx.x * 256 + threadIdx.x;   // coalesced read index
    if (i >= 3 * 128 * 128) return;
    int l = i >> 14;
    int r = i & 16383;
    int k = r >> 7;
    int n = r & 127;
    Wh[(size_t)l * 16384 + n * 128 + k] = f2h(Wall[i]);
}

// ---------------------------------------------------------------------------
// CSR build, XCD-partitioned bucket sort. Degree counting folded in
// (deletes the separate count_deg_b 13.6MB re-read pass).
// ---------------------------------------------------------------------------
__global__ __launch_bounds__(256) void bucket_edges(const int* __restrict__ ei,
                                                    int* __restrict__ bucket_next,
                                                    int2* __restrict__ buckets,
                                                    int* __restrict__ deg) {
    __shared__ int cnt[NBUCK];
    __shared__ int base[NBUCK];
    int tid = threadIdx.x;
    if (tid < NBUCK) cnt[tid] = 0;
    __syncthreads();
    int m = blockIdx.x * 256 + tid;
    int src = 0, dst = 0, p = 0, myoff = 0;
    bool valid = (m < M_TOT);
    if (valid) {
        if (m < N_EDGES) { src = ei[m]; dst = ei[N_EDGES + m]; }
        else             { src = m - N_EDGES; dst = src; }
        p = dst / BUCK_NODES;
        myoff = atomicAdd(&cnt[p], 1);
        atomicAdd(&deg[dst], 1);
    }
    __syncthreads();
    if (tid < NBUCK) base[tid] = (cnt[tid] > 0) ? atomicAdd(&bucket_next[tid], cnt[tid]) : 0;
    __syncthreads();
    if (valid) {
        buckets[(size_t)p * BUCK_CAP + base[p] + myoff] = make_int2(src, dst);
    }
}

__global__ __launch_bounds__(256) void scatter_b(const int2* __restrict__ buckets,
                                                 const int* __restrict__ bucket_next,
                                                 int* __restrict__ nextp,
                                                 int* __restrict__ csr_src) {
    int p = blockIdx.x & 7;
    int chunk = blockIdx.x >> 3;
    int len = bucket_next[p];
    const int2* b = buckets + (size_t)p * BUCK_CAP;
    int stride = (gridDim.x >> 3) * 256;
    for (int i = chunk * 256 + threadIdx.x; i < len; i += stride) {
        int2 e = b[i];
        int pos = atomicAdd(&nextp[e.y], 1);
        csr_src[pos] = e.x;
    }
}

// ---------------------------------------------------------------------------
// prefix scan over deg -> row_ptr / nextp
// ---------------------------------------------------------------------------
__global__ __launch_bounds__(256) void block_sums(const int* __restrict__ deg,
                                                  int* __restrict__ partials) {
    __shared__ int lds[256];
    int base = blockIdx.x * 1024;
    int s = 0;
    for (int i = threadIdx.x; i < 1024; i += 256) {
        int idx = base + i;
        if (idx < N_NODES) s += deg[idx];
    }
    lds[threadIdx.x] = s;
    __syncthreads();
    for (int off = 128; off > 0; off >>= 1) {
        if (threadIdx.x < off) lds[threadIdx.x] += lds[threadIdx.x + off];
        __syncthreads();
    }
    if (threadIdx.x == 0) partials[blockIdx.x] = lds[0];
}

__global__ __launch_bounds__(128) void scan_partials(int* __restrict__ partials, int nb,
                                                     int* __restrict__ row_ptr) {
    __shared__ int lds[128];
    int tid = threadIdx.x;
    int v = (tid < nb) ? partials[tid] : 0;
    lds[tid] = v;
    __syncthreads();
    for (int off = 1; off < 128; off <<= 1) {
        int t = (tid >= off) ? lds[tid - off] : 0;
        __syncthreads();
        lds[tid] += t;
        __syncthreads();
    }
    if (tid < nb) partials[tid] = lds[tid] - v;   // exclusive
    if (tid == 0) row_ptr[N_NODES] = M_TOT;
}

__global__ __launch_bounds__(256) void scan_write(const int* __restrict__ deg,
                                                  const int* __restrict__ partials,
                                                  int* __restrict__ row_ptr,
                                                  int* __restrict__ nextp) {
    __shared__ int lds[256];
    int tid = threadIdx.x;
    int base = blockIdx.x * 1024;
    int i0 = base + tid * 4;
    int d[4];
#pragma unroll
    for (int t = 0; t < 4; ++t)
        d[t] = (i0 + t < N_NODES) ? deg[i0 + t] : 0;
    int tsum = d[0] + d[1] + d[2] + d[3];
    lds[tid] = tsum;
    __syncthreads();
    for (int off = 1; off < 256; off <<= 1) {
        int v = (tid >= off) ? lds[tid - off] : 0;
        __syncthreads();
        lds[tid] += v;
        __syncthreads();
    }
    int excl = lds[tid] - tsum;
    int run = partials[blockIdx.x] + excl;
#pragma unroll
    for (int t = 0; t < 4; ++t) {
        if (i0 + t < N_NODES) {
            row_ptr[i0 + t] = run;
            nextp[i0 + t]   = run;
            run += d[t];
        }
    }
}

// ---------------------------------------------------------------------------
// LDS-free-staging MFMA fp16 GEMM, 64-row tiles (1563 blocks ~= 6.1/CU for
// latency hiding). Each wave owns 16 rows; A loaded directly from global
// (each element once), W from pre-converted fp16 Wh (L1/L2-resident).
// BN apply of the previous layer fused into the A load (layers >= 1).
// Hh output staged through LDS for coalesced 16B stores.
// ---------------------------------------------------------------------------
__global__ __launch_bounds__(256, 4) void gemm_attn(
    const float* __restrict__ X, int ldx,
    const unsigned short* __restrict__ Wh,
    const float* __restrict__ a_src, const float* __restrict__ a_dst,
    const float* __restrict__ gbv,           // nullptr for layer 0
    float* __restrict__ outw,                // out slice of previous layer
    unsigned short* __restrict__ Hh, float* __restrict__ Ssrc,
    float* __restrict__ Sdst) {
    __shared__ unsigned short Hs[64 * HS_LD];   // 17 KB
    int tid = threadIdx.x;
    int wave = tid >> 6;
    int lane = tid & 63;
    int q = lane >> 4;
    int l15 = lane & 15;
    int wrow = wave * 16;
    int rbase = blockIdx.x * 64;

    int row0 = rbase + wrow + l15;
    bool ok0 = row0 < N_NODES;
    int r0c = ok0 ? row0 : (N_NODES - 1);

    f32x4 acc[8] = {};

#pragma unroll
    for (int ks = 0; ks < 128; ks += 32) {
        int k0 = ks + q * 8;
        float4 v0 = *(const float4*)&X[(size_t)r0c * ldx + k0];
        float4 v1 = *(const float4*)&X[(size_t)r0c * ldx + k0 + 4];
        if (gbv) {
            float4 g0 = *(const float4*)&gbv[k0];
            float4 g1 = *(const float4*)&gbv[k0 + 4];
            float4 b0 = *(const float4*)&gbv[128 + k0];
            float4 b1 = *(const float4*)&gbv[128 + k0 + 4];
            v0.x = fmaf(v0.x, g0.x, b0.x); v0.y = fmaf(v0.y, g0.y, b0.y);
            v0.z = fmaf(v0.z, g0.z, b0.z); v0.w = fmaf(v0.w, g0.w, b0.w);
            v1.x = fmaf(v1.x, g1.x, b1.x); v1.y = fmaf(v1.y, g1.y, b1.y);
            v1.z = fmaf(v1.z, g1.z, b1.z); v1.w = fmaf(v1.w, g1.w, b1.w);
            if (ok0) {
                *(float4*)&outw[(size_t)row0 * 384 + k0] = v0;
                *(float4*)&outw[(size_t)row0 * 384 + k0 + 4] = v1;
            }
        }
        f16x8 a;
        a[0] = f2h16(v0.x); a[1] = f2h16(v0.y); a[2] = f2h16(v0.z); a[3] = f2h16(v0.w);
        a[4] = f2h16(v1.x); a[5] = f2h16(v1.y); a[6] = f2h16(v1.z); a[7] = f2h16(v1.w);
#pragma unroll
        for (int c = 0; c < 8; ++c) {
            f16x8 b = *(const f16x8*)&Wh[(size_t)(c * 16 + l15) * 128 + k0];
            acc[c] = __builtin_amdgcn_mfma_f32_16x16x32_f16(a, b, acc[c], 0, 0, 0);
        }
    }

    // attention dot products (C/D layout: col=lane&15, row=(lane>>4)*4+reg)
    float avs[8], avd[8];
#pragma unroll
    for (int c = 0; c < 8; ++c) {
        avs[c] = a_src[c * 16 + l15];
        avd[c] = a_dst[c * 16 + l15];
    }
    float ps[4] = {0, 0, 0, 0}, pd[4] = {0, 0, 0, 0};
#pragma unroll
    for (int g = 0; g < 4; ++g) {
#pragma unroll
        for (int c = 0; c < 8; ++c) {
            float h = acc[c][g];
            ps[g] = fmaf(h, avs[c], ps[g]);
            pd[g] = fmaf(h, avd[c], pd[g]);
        }
    }
#pragma unroll
    for (int g = 0; g < 4; ++g) {
#pragma unroll
        for (int off = 1; off < 16; off <<= 1) {
            ps[g] += __shfl_xor(ps[g], off, 64);
            pd[g] += __shfl_xor(pd[g], off, 64);
        }
    }
    if (l15 == 0) {
#pragma unroll
        for (int g = 0; g < 4; ++g) {
            int row = rbase + wrow + q * 4 + g;
            if (row < N_NODES) {
                Ssrc[row] = ps[g];
                Sdst[row] = pd[g];
            }
        }
    }

    // Hh store via LDS staging -> coalesced 16B global stores.
    // 64 rows x 128 cols = 8192 shorts; 4 iters x 256 thr x f16x8 = 8192.
#pragma unroll
    for (int c = 0; c < 8; ++c) {
#pragma unroll
        for (int g = 0; g < 4; ++g) {
            Hs[(wrow + q * 4 + g) * HS_LD + c * 16 + l15] = f2h(acc[c][g]);
        }
    }
    __syncthreads();
#pragma unroll
    for (int i = 0; i < 4; ++i) {
        int idx = i * 256 + tid;
        int lr = idx >> 4;            // 0..63
        int cg = (idx & 15) * 8;      // 0,8,...,120
        int grow = rbase + lr;
        if (grow < N_NODES) {
            *(f16x8*)&Hh[(size_t)grow * 128 + cg] =
                *(const f16x8*)&Hs[lr * HS_LD + cg];
        }
    }
}

// ---------------------------------------------------------------------------
// Per-node softmax + weighted aggregation.
// Self-loop score as softmax anchor (exact via shift-invariance).
// 4 edges per wave (16 lanes x f16x8 = full 256B row per edge slot);
// 4-deep chain unroll (16 edges/iter) for memory-level parallelism.
// ---------------------------------------------------------------------------
__global__ __launch_bounds__(256) void aggregate(
    const unsigned short* __restrict__ Hh, const int* __restrict__ row_ptr,
    const int* __restrict__ csr_src,
    const float* __restrict__ Ssrc, const float* __restrict__ Sdst,
    const float* __restrict__ bias, float* __restrict__ Y) {
    int wave = threadIdx.x >> 6;
    int lane = threadIdx.x & 63;
    int g = lane >> 4;               // edge slot 0..3
    int l15 = lane & 15;             // channel group: ch = l15*8 + i
    int v = blockIdx.x * 4 + wave;
    int start = row_ptr[v];
    int end = row_ptr[v + 1];
    float sdv = Sdst[v];

    // anchor = self-loop score (exact softmax shift-invariance)
    float sself = Ssrc[v] + sdv;
    float m = (sself > 0.0f) ? sself : NEG_SLOPE * sself;

    float acc[8] = {0, 0, 0, 0, 0, 0, 0, 0};
    float denom = 0.0f;

    int j = start;
    for (; j + 16 <= end; j += 16) {
        int u0 = csr_src[j + g];
        int u1 = csr_src[j + 4 + g];
        int u2 = csr_src[j + 8 + g];
        int u3 = csr_src[j + 12 + g];
        float ss0 = Ssrc[u0];
        float ss1 = Ssrc[u1];
        float ss2 = Ssrc[u2];
        float ss3 = Ssrc[u3];
        f16x8 h0 = *(const f16x8*)&Hh[(size_t)u0 * 128 + l15 * 8];
        f16x8 h1 = *(const f16x8*)&Hh[(size_t)u1 * 128 + l15 * 8];
        f16x8 h2 = *(const f16x8*)&Hh[(size_t)u2 * 128 + l15 * 8];
        f16x8 h3 = *(const f16x8*)&Hh[(size_t)u3 * 128 + l15 * 8];
        float s0 = ss0 + sdv; s0 = (s0 > 0.0f) ? s0 : NEG_SLOPE * s0;
        float s1 = ss1 + sdv; s1 = (s1 > 0.0f) ? s1 : NEG_SLOPE * s1;
        float s2 = ss2 + sdv; s2 = (s2 > 0.0f) ? s2 : NEG_SLOPE * s2;
        float s3 = ss3 + sdv; s3 = (s3 > 0.0f) ? s3 : NEG_SLOPE * s3;
        float w0 = __expf(s0 - m);
        float w1 = __expf(s1 - m);
        float w2 = __expf(s2 - m);
        float w3 = __expf(s3 - m);
        denom += (w0 + w1) + (w2 + w3);
#pragma unroll
        for (int i = 0; i < 8; ++i) acc[i] = fmaf(w0, (float)h0[i], acc[i]);
#pragma unroll
        for (int i = 0; i < 8; ++i) acc[i] = fmaf(w1, (float)h1[i], acc[i]);
#pragma unroll
        for (int i = 0; i < 8; ++i) acc[i] = fmaf(w2, (float)h2[i], acc[i]);
#pragma unroll
        for (int i = 0; i < 8; ++i) acc[i] = fmaf(w3, (float)h3[i], acc[i]);
    }
    for (; j + 8 <= end; j += 8) {
        int u0 = csr_src[j + g];
        int u1 = csr_src[j + 4 + g];
        float ss0 = Ssrc[u0];
        float ss1 = Ssrc[u1];
        f16x8 h0 = *(const f16x8*)&Hh[(size_t)u0 * 128 + l15 * 8];
        f16x8 h1 = *(const f16x8*)&Hh[(size_t)u1 * 128 + l15 * 8];
        float s0 = ss0 + sdv; s0 = (s0 > 0.0f) ? s0 : NEG_SLOPE * s0;
        float s1 = ss1 + sdv; s1 = (s1 > 0.0f) ? s1 : NEG_SLOPE * s1;
        float w0 = __expf(s0 - m);
        float w1 = __expf(s1 - m);
        denom += w0 + w1;
#pragma unroll
        for (int i = 0; i < 8; ++i) acc[i] = fmaf(w0, (float)h0[i], acc[i]);
#pragma unroll
        for (int i = 0; i < 8; ++i) acc[i] = fmaf(w1, (float)h1[i], acc[i]);
    }
    for (; j < end; j += 4) {
        int je = j + g;
        bool ok = (je < end);
        int u = ok ? csr_src[je] : v;
        float s = Ssrc[u] + sdv; s = (s > 0.0f) ? s : NEG_SLOPE * s;
        float w = ok ? __expf(s - m) : 0.0f;
        f16x8 h = *(const f16x8*)&Hh[(size_t)u * 128 + l15 * 8];
        denom += w;
#pragma unroll
        for (int i = 0; i < 8; ++i) acc[i] = fmaf(w, (float)h[i], acc[i]);
    }

    // combine the 4 edge slots (lane bits 4 and 5)
#pragma unroll
    for (int i = 0; i < 8; ++i) {
        acc[i] += __shfl_xor(acc[i], 16, 64);
        acc[i] += __shfl_xor(acc[i], 32, 64);
    }
    denom += __shfl_xor(denom, 16, 64);
    denom += __shfl_xor(denom, 32, 64);

    if (g == 0) {
        float inv = 1.0f / denom;
        float4 b0 = *(const float4*)&bias[l15 * 8];
        float4 b1 = *(const float4*)&bias[l15 * 8 + 4];
        float4 o0, o1;
        o0.x = fmaxf(fmaf(acc[0], inv, b0.x), 0.0f);
        o0.y = fmaxf(fmaf(acc[1], inv, b0.y), 0.0f);
        o0.z = fmaxf(fmaf(acc[2], inv, b0.z), 0.0f);
        o0.w = fmaxf(fmaf(acc[3], inv, b0.w), 0.0f);
        o1.x = fmaxf(fmaf(acc[4], inv, b1.x), 0.0f);
        o1.y = fmaxf(fmaf(acc[5], inv, b1.y), 0.0f);
        o1.z = fmaxf(fmaf(acc[6], inv, b1.z), 0.0f);
        o1.w = fmaxf(fmaf(acc[7], inv, b1.w), 0.0f);
        *(float4*)&Y[(size_t)v * 128 + l15 * 8] = o0;
        *(float4*)&Y[(size_t)v * 128 + l15 * 8 + 4] = o1;
    }
}

// ---------------------------------------------------------------------------
// BatchNorm stats / finalize / apply (apply only used for the last layer;
// layers 0-1 are applied inside the next gemm_attn's A-load).
// ---------------------------------------------------------------------------
__global__ __launch_bounds__(256) void bn_stats(const float* __restrict__ Y,
                                                float* __restrict__ partial) {
    __shared__ float red[256 * 8];    // 8 KB
    int tid = threadIdx.x;
    int rowlane = tid >> 5;           // 0..7
    int cg = tid & 31;                // col-group of 4
    float4 s = make_float4(0, 0, 0, 0);
    float4 qq = make_float4(0, 0, 0, 0);
    for (int i = blockIdx.x * 8 + rowlane; i < N_NODES; i += BN_NB * 8) {
        float4 v = *(const float4*)&Y[(size_t)i * 128 + cg * 4];
        s.x += v.x; s.y += v.y; s.z += v.z; s.w += v.w;
        qq.x = fmaf(v.x, v.x, qq.x);
        qq.y = fmaf(v.y, v.y, qq.y);
        qq.z = fmaf(v.z, v.z, qq.z);
        qq.w = fmaf(v.w, v.w, qq.w);
    }
    float* r = &red[tid * 8];
    r[0] = s.x; r[1] = s.y; r[2] = s.z; r[3] = s.w;
    r[4] = qq.x; r[5] = qq.y; r[6] = qq.z; r[7] = qq.w;
    __syncthreads();
    for (int off = 4; off > 0; off >>= 1) {
        if (rowlane < off) {
            float* o = &red[(tid + off * 32) * 8];
#pragma unroll
            for (int t = 0; t < 8; ++t) r[t] += o[t];
        }
        __syncthreads();
    }
    if (rowlane == 0) {
        *(float4*)&partial[(size_t)blockIdx.x * 256 + cg * 4] =
            make_float4(r[0], r[1], r[2], r[3]);
        *(float4*)&partial[(size_t)blockIdx.x * 256 + 128 + cg * 4] =
            make_float4(r[4], r[5], r[6], r[7]);
    }
}

__global__ __launch_bounds__(256) void bn_finalize(const float* __restrict__ partial,
                                                   const float* __restrict__ gamma,
                                                   const float* __restrict__ beta,
                                                   float* __restrict__ gb) {
    __shared__ float tot[256];
    int tid = threadIdx.x;
    float acc = 0.0f;
    for (int b = 0; b < BN_NB; ++b) acc += partial[(size_t)b * 256 + tid];
    tot[tid] = acc;
    __syncthreads();
    if (tid < 128) {
        const float invN = 1.0f / (float)N_NODES;
        float mu = tot[tid] * invN;
        float var = tot[128 + tid] * invN - mu * mu;
        float g = gamma[tid] * rsqrtf(var + BN_EPS);
        gb[tid] = g;
        gb[128 + tid] = beta[tid] - mu * g;
    }
}

__global__ __launch_bounds__(256) void bn_apply(const float* __restrict__ Y,
                                                const float* __restrict__ gb,
                                                float* __restrict__ out) {
    int idx = blockIdx.x * blockDim.x + threadIdx.x;
    if (idx >= N_NODES * 32) return;
    int row = idx >> 5;
    int c4 = (idx & 31) * 4;
    float4 v = *(const float4*)&Y[(size_t)row * 128 + c4];
    float4 g = *(const float4*)&gb[c4];
    float4 b = *(const float4*)&gb[128 + c4];
    v.x = fmaf(v.x, g.x, b.x);
    v.y = fmaf(v.y, g.y, b.y);
    v.z = fmaf(v.z, g.z, b.z);
    v.w = fmaf(v.w, g.w, b.w);
    *(float4*)&out[(size_t)row * 384 + c4] = v;
}

// ---------------------------------------------------------------------------
// driver
// ---------------------------------------------------------------------------
extern "C" void kernel_launch(void* const* d_in, const int* in_sizes, int n_in,
                              void* d_out, int out_size, void* d_ws, size_t ws_size,
                              hipStream_t stream) {
    const float* x      = (const float*)d_in[0];
    const int*   ei     = (const int*)d_in[1];   // [2, E] int32
    const float* Wall   = (const float*)d_in[2];
    const float* asrcs  = (const float*)d_in[3];
    const float* adsts  = (const float*)d_in[4];
    const float* biases = (const float*)d_in[5];
    const float* gammas = (const float*)d_in[6];
    const float* betas  = (const float*)d_in[7];
    float* out = (float*)d_out;

    // workspace layout
    unsigned short* Hh = (unsigned short*)d_ws;              // N*128 fp16
    float* Y       = (float*)(Hh + (size_t)N_NODES * 128);   // N*128 fp32
    float* Ssrc    = Y + (size_t)N_NODES * 128;
    float* Sdst    = Ssrc + N_NODES;
    float* bnpart  = Sdst + N_NODES;                         // 256*256
    float* gb      = bnpart + BN_NB * 256;                   // 256
    unsigned short* Wh = (unsigned short*)(gb + 256);        // 3*128*128 fp16 (16B aligned)
    // ---- zero zone (contiguous) ----
    int* deg       = (int*)(Wh + 3 * 128 * 128);             // 100000
    int* bucket_next = deg + N_NODES;                        // 8
    // ---- end zero zone ----
    int* row_ptr   = bucket_next + NBUCK;                    // 100001
    int* nextp     = row_ptr + (N_NODES + 1);                // 100000
    int* partials  = nextp + N_NODES;                        // 128
    int* csr_src   = partials + 128;                         // 1.7M
    int2* buckets  = (int2*)(csr_src + M_TOT + 2);           // 8*240000 int2

    const int ZERO_CNT = N_NODES + NBUCK;
    const int NB_EDGE = (M_TOT + 255) / 256;                 // 6641
    const int NB_PART = 2048;

    // ---- CSR build (bucketed, deg fused) + one-shot W convert ----
    zero_i32<<<(ZERO_CNT + 255) / 256, 256, 0, stream>>>(deg, ZERO_CNT);
    conv_w<<<192, 256, 0, stream>>>(Wall, Wh);
    bucket_edges<<<NB_EDGE, 256, 0, stream>>>(ei, bucket_next, buckets, deg);
    block_sums<<<SCAN_NB, 256, 0, stream>>>(deg, partials);
    scan_partials<<<1, 128, 0, stream>>>(partials, SCAN_NB, row_ptr);
    scan_write<<<SCAN_NB, 256, 0, stream>>>(deg, partials, row_ptr, nextp);
    scatter_b<<<NB_PART, 256, 0, stream>>>(buckets, bucket_next, nextp, csr_src);

    // ---- 3 GAT layers (BN apply of layer l-1 fused into gemm of layer l) ----
    for (int l = 0; l < 3; ++l) {
        const float* xin;
        int ldx;
        const float* gbl;
        float* outw;
        if (l == 0) { xin = x; ldx = 128; gbl = nullptr; outw = nullptr; }
        else        { xin = Y; ldx = 128; gbl = gb; outw = out + (size_t)(l - 1) * 128; }
        gemm_attn<<<(N_NODES + 63) / 64, 256, 0, stream>>>(
            xin, ldx, Wh + (size_t)l * 128 * 128,
            asrcs + l * 128, adsts + l * 128, gbl, outw, Hh, Ssrc, Sdst);
        aggregate<<<N_NODES / 4, 256, 0, stream>>>(
            Hh, row_ptr, csr_src, Ssrc, Sdst, biases + l * 128, Y);
        bn_stats<<<BN_NB, 256, 0, stream>>>(Y, bnpart);
        bn_finalize<<<1, 256, 0, stream>>>(bnpart, gammas + l * 128,
                                           betas + l * 128, gb);
    }
    // final layer's BN apply (no following gemm to fuse into)
    bn_apply<<<(N_NODES * 32 + 255) / 256, 256, 0, stream>>>(
        Y, gb, out + (size_t)2 * 128);
}

// Round 6
// 747.756 us; speedup vs baseline: 1.1716x; 1.0259x over previous
//
#include <hip/hip_runtime.h>
#include <math.h>

#define N_NODES 100000
#define N_EDGES 1600000
#define M_TOT   (N_EDGES + N_NODES)   // edges + self loops = 1,700,000
#define C_DIM   128
#define NEG_SLOPE 0.2f
#define BN_EPS 1e-5f

#define NBUCK 8
#define BUCK_NODES 12500
#define BUCK_CAP 240000

#define BN_NB 256                     // bn_stats blocks
#define SCAN_NB 98                    // ceil(100000/1024)
#define HS_LD 136                     // LDS halves stride (272B, 16B-aligned)

#define EB_TPB 512                    // bucket_edges block size

typedef _Float16 f16x8 __attribute__((ext_vector_type(8)));
typedef float f32x4 __attribute__((ext_vector_type(4)));

static __device__ __forceinline__ unsigned short f2h(float f) {
    _Float16 h = (_Float16)f;
    unsigned short u;
    __builtin_memcpy(&u, &h, 2);
    return u;
}
static __device__ __forceinline__ float h2f(unsigned short u) {
    _Float16 h;
    __builtin_memcpy(&h, &u, 2);
    return (float)h;
}
static __device__ __forceinline__ _Float16 f2h16(float f) { return (_Float16)f; }

// ---------------------------------------------------------------------------
// utility
// ---------------------------------------------------------------------------
__global__ void zero_i32(int* __restrict__ p, int n) {
    int i = blockIdx.x * blockDim.x + threadIdx.x;
    if (i < n) p[i] = 0;
}

// One-shot: convert all 3 W matrices to fp16, transposed to n-major:
// Wh[l][n][k] = (fp16) W[l][k][n].  32KB per layer -> L1/L2-resident in gemm.
__global__ __launch_bounds__(256) void conv_w(const float* __restrict__ Wall,
                                              unsigned short* __restrict__ Wh) {
    int i = blockIdx.x * 256 + threadIdx.x;   // coalesced read index
    if (i >= 3 * 128 * 128) return;
    int l = i >> 14;
    int r = i & 16383;
    int k = r >> 7;
    int n = r & 127;
    Wh[(size_t)l * 16384 + n * 128 + k] = f2h(Wall[i]);
}

// ---------------------------------------------------------------------------
// CSR build, XCD-partitioned bucket sort. Degree counting fused.
// Wave-ballot counting (8 LDS atomics/wave instead of 64 same-address ones)
// + LDS staging so bucket writes flush as contiguous coalesced runs
// (fixes the 5x write amplification seen in rocprof: WRITE_SIZE 65MB for
// 13.6MB of useful bucket data).
// ---------------------------------------------------------------------------
__global__ __launch_bounds__(EB_TPB) void bucket_edges(const int* __restrict__ ei,
                                                       int* __restrict__ bucket_next,
                                                       int2* __restrict__ buckets,
                                                       int* __restrict__ deg) {
    __shared__ int2 stage[NBUCK * EB_TPB];   // 32 KB
    __shared__ int cnt[NBUCK];
    __shared__ int base[NBUCK];
    int tid = threadIdx.x;
    int lane = tid & 63;
    if (tid < NBUCK) cnt[tid] = 0;
    __syncthreads();

    int m = blockIdx.x * EB_TPB + tid;
    bool valid = (m < M_TOT);
    int src = 0, dst = 0, p = 0;
    if (valid) {
        if (m < N_EDGES) { src = ei[m]; dst = ei[N_EDGES + m]; }
        else             { src = m - N_EDGES; dst = src; }
        p = dst / BUCK_NODES;
        atomicAdd(&deg[dst], 1);
    }

    int myoff = 0;
#pragma unroll
    for (int b = 0; b < NBUCK; ++b) {
        unsigned long long mask = __ballot(valid && (p == b));
        if (mask) {
            int cntb = __popcll(mask);
            int leader = __ffsll((unsigned long long)mask) - 1;
            int wbase = 0;
            if (lane == leader) wbase = atomicAdd(&cnt[b], cntb);
            wbase = __shfl(wbase, leader, 64);
            if (valid && (p == b))
                myoff = wbase + __popcll(mask & ((1ull << lane) - 1ull));
        }
    }
    if (valid) stage[p * EB_TPB + myoff] = make_int2(src, dst);
    __syncthreads();

    if (tid < NBUCK) base[tid] = (cnt[tid] > 0) ? atomicAdd(&bucket_next[tid], cnt[tid]) : 0;
    __syncthreads();

#pragma unroll
    for (int b = 0; b < NBUCK; ++b) {
        int c = cnt[b];
        int2* dp = buckets + (size_t)b * BUCK_CAP + base[b];
        const int2* sp = &stage[b * EB_TPB];
        for (int i = tid; i < c; i += EB_TPB) dp[i] = sp[i];
    }
}

__global__ __launch_bounds__(256) void scatter_b(const int2* __restrict__ buckets,
                                                 const int* __restrict__ bucket_next,
                                                 int* __restrict__ nextp,
                                                 int* __restrict__ csr_src) {
    int p = blockIdx.x & 7;
    int chunk = blockIdx.x >> 3;
    int len = bucket_next[p];
    const int2* b = buckets + (size_t)p * BUCK_CAP;
    int stride = (gridDim.x >> 3) * 256;
    for (int i = chunk * 256 + threadIdx.x; i < len; i += stride) {
        int2 e = b[i];
        int pos = atomicAdd(&nextp[e.y], 1);
        csr_src[pos] = e.x;
    }
}

// ---------------------------------------------------------------------------
// prefix scan over deg -> row_ptr / nextp
// ---------------------------------------------------------------------------
__global__ __launch_bounds__(256) void block_sums(const int* __restrict__ deg,
                                                  int* __restrict__ partials) {
    __shared__ int lds[256];
    int base = blockIdx.x * 1024;
    int s = 0;
    for (int i = threadIdx.x; i < 1024; i += 256) {
        int idx = base + i;
        if (idx < N_NODES) s += deg[idx];
    }
    lds[threadIdx.x] = s;
    __syncthreads();
    for (int off = 128; off > 0; off >>= 1) {
        if (threadIdx.x < off) lds[threadIdx.x] += lds[threadIdx.x + off];
        __syncthreads();
    }
    if (threadIdx.x == 0) partials[blockIdx.x] = lds[0];
}

__global__ __launch_bounds__(128) void scan_partials(int* __restrict__ partials, int nb,
                                                     int* __restrict__ row_ptr) {
    __shared__ int lds[128];
    int tid = threadIdx.x;
    int v = (tid < nb) ? partials[tid] : 0;
    lds[tid] = v;
    __syncthreads();
    for (int off = 1; off < 128; off <<= 1) {
        int t = (tid >= off) ? lds[tid - off] : 0;
        __syncthreads();
        lds[tid] += t;
        __syncthreads();
    }
    if (tid < nb) partials[tid] = lds[tid] - v;   // exclusive
    if (tid == 0) row_ptr[N_NODES] = M_TOT;
}

__global__ __launch_bounds__(256) void scan_write(const int* __restrict__ deg,
                                                  const int* __restrict__ partials,
                                                  int* __restrict__ row_ptr,
                                                  int* __restrict__ nextp) {
    __shared__ int lds[256];
    int tid = threadIdx.x;
    int base = blockIdx.x * 1024;
    int i0 = base + tid * 4;
    int d[4];
#pragma unroll
    for (int t = 0; t < 4; ++t)
        d[t] = (i0 + t < N_NODES) ? deg[i0 + t] : 0;
    int tsum = d[0] + d[1] + d[2] + d[3];
    lds[tid] = tsum;
    __syncthreads();
    for (int off = 1; off < 256; off <<= 1) {
        int v = (tid >= off) ? lds[tid - off] : 0;
        __syncthreads();
        lds[tid] += v;
        __syncthreads();
    }
    int excl = lds[tid] - tsum;
    int run = partials[blockIdx.x] + excl;
#pragma unroll
    for (int t = 0; t < 4; ++t) {
        if (i0 + t < N_NODES) {
            row_ptr[i0 + t] = run;
            nextp[i0 + t]   = run;
            run += d[t];
        }
    }
}

// ---------------------------------------------------------------------------
// LDS-free-staging MFMA fp16 GEMM, 64-row tiles (1563 blocks ~= 6.1/CU for
// latency hiding). Each wave owns 16 rows; A loaded directly from global
// (each element once), W from pre-converted fp16 Wh (L1/L2-resident).
// BN apply of the previous layer fused into the A load (layers >= 1).
// Hh output staged through LDS for coalesced 16B stores.
// ---------------------------------------------------------------------------
__global__ __launch_bounds__(256, 4) void gemm_attn(
    const float* __restrict__ X, int ldx,
    const unsigned short* __restrict__ Wh,
    const float* __restrict__ a_src, const float* __restrict__ a_dst,
    const float* __restrict__ gbv,           // nullptr for layer 0
    float* __restrict__ outw,                // out slice of previous layer
    unsigned short* __restrict__ Hh, float* __restrict__ Ssrc,
    float* __restrict__ Sdst) {
    __shared__ unsigned short Hs[64 * HS_LD];   // 17 KB
    int tid = threadIdx.x;
    int wave = tid >> 6;
    int lane = tid & 63;
    int q = lane >> 4;
    int l15 = lane & 15;
    int wrow = wave * 16;
    int rbase = blockIdx.x * 64;

    int row0 = rbase + wrow + l15;
    bool ok0 = row0 < N_NODES;
    int r0c = ok0 ? row0 : (N_NODES - 1);

    f32x4 acc[8] = {};

#pragma unroll
    for (int ks = 0; ks < 128; ks += 32) {
        int k0 = ks + q * 8;
        float4 v0 = *(const float4*)&X[(size_t)r0c * ldx + k0];
        float4 v1 = *(const float4*)&X[(size_t)r0c * ldx + k0 + 4];
        if (gbv) {
            float4 g0 = *(const float4*)&gbv[k0];
            float4 g1 = *(const float4*)&gbv[k0 + 4];
            float4 b0 = *(const float4*)&gbv[128 + k0];
            float4 b1 = *(const float4*)&gbv[128 + k0 + 4];
            v0.x = fmaf(v0.x, g0.x, b0.x); v0.y = fmaf(v0.y, g0.y, b0.y);
            v0.z = fmaf(v0.z, g0.z, b0.z); v0.w = fmaf(v0.w, g0.w, b0.w);
            v1.x = fmaf(v1.x, g1.x, b1.x); v1.y = fmaf(v1.y, g1.y, b1.y);
            v1.z = fmaf(v1.z, g1.z, b1.z); v1.w = fmaf(v1.w, g1.w, b1.w);
            if (ok0) {
                *(float4*)&outw[(size_t)row0 * 384 + k0] = v0;
                *(float4*)&outw[(size_t)row0 * 384 + k0 + 4] = v1;
            }
        }
        f16x8 a;
        a[0] = f2h16(v0.x); a[1] = f2h16(v0.y); a[2] = f2h16(v0.z); a[3] = f2h16(v0.w);
        a[4] = f2h16(v1.x); a[5] = f2h16(v1.y); a[6] = f2h16(v1.z); a[7] = f2h16(v1.w);
#pragma unroll
        for (int c = 0; c < 8; ++c) {
            f16x8 b = *(const f16x8*)&Wh[(size_t)(c * 16 + l15) * 128 + k0];
            acc[c] = __builtin_amdgcn_mfma_f32_16x16x32_f16(a, b, acc[c], 0, 0, 0);
        }
    }

    // attention dot products (C/D layout: col=lane&15, row=(lane>>4)*4+reg)
    float avs[8], avd[8];
#pragma unroll
    for (int c = 0; c < 8; ++c) {
        avs[c] = a_src[c * 16 + l15];
        avd[c] = a_dst[c * 16 + l15];
    }
    float ps[4] = {0, 0, 0, 0}, pd[4] = {0, 0, 0, 0};
#pragma unroll
    for (int g = 0; g < 4; ++g) {
#pragma unroll
        for (int c = 0; c < 8; ++c) {
            float h = acc[c][g];
            ps[g] = fmaf(h, avs[c], ps[g]);
            pd[g] = fmaf(h, avd[c], pd[g]);
        }
    }
#pragma unroll
    for (int g = 0; g < 4; ++g) {
#pragma unroll
        for (int off = 1; off < 16; off <<= 1) {
            ps[g] += __shfl_xor(ps[g], off, 64);
            pd[g] += __shfl_xor(pd[g], off, 64);
        }
    }
    if (l15 == 0) {
#pragma unroll
        for (int g = 0; g < 4; ++g) {
            int row = rbase + wrow + q * 4 + g;
            if (row < N_NODES) {
                Ssrc[row] = ps[g];
                Sdst[row] = pd[g];
            }
        }
    }

    // Hh store via LDS staging -> coalesced 16B global stores.
    // 64 rows x 128 cols = 8192 shorts; 4 iters x 256 thr x f16x8 = 8192.
#pragma unroll
    for (int c = 0; c < 8; ++c) {
#pragma unroll
        for (int g = 0; g < 4; ++g) {
            Hs[(wrow + q * 4 + g) * HS_LD + c * 16 + l15] = f2h(acc[c][g]);
        }
    }
    __syncthreads();
#pragma unroll
    for (int i = 0; i < 4; ++i) {
        int idx = i * 256 + tid;
        int lr = idx >> 4;            // 0..63
        int cg = (idx & 15) * 8;      // 0,8,...,120
        int grow = rbase + lr;
        if (grow < N_NODES) {
            *(f16x8*)&Hh[(size_t)grow * 128 + cg] =
                *(const f16x8*)&Hs[lr * HS_LD + cg];
        }
    }
}

// ---------------------------------------------------------------------------
// Per-node softmax + weighted aggregation.
// Self-loop score as softmax anchor (exact via shift-invariance).
// 4 edges per wave (16 lanes x f16x8 = full 256B row per edge slot);
// 4-deep chain unroll (16 edges/iter) for memory-level parallelism.
// ---------------------------------------------------------------------------
__global__ __launch_bounds__(256) void aggregate(
    const unsigned short* __restrict__ Hh, const int* __restrict__ row_ptr,
    const int* __restrict__ csr_src,
    const float* __restrict__ Ssrc, const float* __restrict__ Sdst,
    const float* __restrict__ bias, float* __restrict__ Y) {
    int wave = threadIdx.x >> 6;
    int lane = threadIdx.x & 63;
    int g = lane >> 4;               // edge slot 0..3
    int l15 = lane & 15;             // channel group: ch = l15*8 + i
    int v = blockIdx.x * 4 + wave;
    int start = row_ptr[v];
    int end = row_ptr[v + 1];
    float sdv = Sdst[v];

    // anchor = self-loop score (exact softmax shift-invariance)
    float sself = Ssrc[v] + sdv;
    float m = (sself > 0.0f) ? sself : NEG_SLOPE * sself;

    float acc[8] = {0, 0, 0, 0, 0, 0, 0, 0};
    float denom = 0.0f;

    int j = start;
    for (; j + 16 <= end; j += 16) {
        int u0 = csr_src[j + g];
        int u1 = csr_src[j + 4 + g];
        int u2 = csr_src[j + 8 + g];
        int u3 = csr_src[j + 12 + g];
        float ss0 = Ssrc[u0];
        float ss1 = Ssrc[u1];
        float ss2 = Ssrc[u2];
        float ss3 = Ssrc[u3];
        f16x8 h0 = *(const f16x8*)&Hh[(size_t)u0 * 128 + l15 * 8];
        f16x8 h1 = *(const f16x8*)&Hh[(size_t)u1 * 128 + l15 * 8];
        f16x8 h2 = *(const f16x8*)&Hh[(size_t)u2 * 128 + l15 * 8];
        f16x8 h3 = *(const f16x8*)&Hh[(size_t)u3 * 128 + l15 * 8];
        float s0 = ss0 + sdv; s0 = (s0 > 0.0f) ? s0 : NEG_SLOPE * s0;
        float s1 = ss1 + sdv; s1 = (s1 > 0.0f) ? s1 : NEG_SLOPE * s1;
        float s2 = ss2 + sdv; s2 = (s2 > 0.0f) ? s2 : NEG_SLOPE * s2;
        float s3 = ss3 + sdv; s3 = (s3 > 0.0f) ? s3 : NEG_SLOPE * s3;
        float w0 = __expf(s0 - m);
        float w1 = __expf(s1 - m);
        float w2 = __expf(s2 - m);
        float w3 = __expf(s3 - m);
        denom += (w0 + w1) + (w2 + w3);
#pragma unroll
        for (int i = 0; i < 8; ++i) acc[i] = fmaf(w0, (float)h0[i], acc[i]);
#pragma unroll
        for (int i = 0; i < 8; ++i) acc[i] = fmaf(w1, (float)h1[i], acc[i]);
#pragma unroll
        for (int i = 0; i < 8; ++i) acc[i] = fmaf(w2, (float)h2[i], acc[i]);
#pragma unroll
        for (int i = 0; i < 8; ++i) acc[i] = fmaf(w3, (float)h3[i], acc[i]);
    }
    for (; j + 8 <= end; j += 8) {
        int u0 = csr_src[j + g];
        int u1 = csr_src[j + 4 + g];
        float ss0 = Ssrc[u0];
        float ss1 = Ssrc[u1];
        f16x8 h0 = *(const f16x8*)&Hh[(size_t)u0 * 128 + l15 * 8];
        f16x8 h1 = *(const f16x8*)&Hh[(size_t)u1 * 128 + l15 * 8];
        float s0 = ss0 + sdv; s0 = (s0 > 0.0f) ? s0 : NEG_SLOPE * s0;
        float s1 = ss1 + sdv; s1 = (s1 > 0.0f) ? s1 : NEG_SLOPE * s1;
        float w0 = __expf(s0 - m);
        float w1 = __expf(s1 - m);
        denom += w0 + w1;
#pragma unroll
        for (int i = 0; i < 8; ++i) acc[i] = fmaf(w0, (float)h0[i], acc[i]);
#pragma unroll
        for (int i = 0; i < 8; ++i) acc[i] = fmaf(w1, (float)h1[i], acc[i]);
    }
    for (; j < end; j += 4) {
        int je = j + g;
        bool ok = (je < end);
        int u = ok ? csr_src[je] : v;
        float s = Ssrc[u] + sdv; s = (s > 0.0f) ? s : NEG_SLOPE * s;
        float w = ok ? __expf(s - m) : 0.0f;
        f16x8 h = *(const f16x8*)&Hh[(size_t)u * 128 + l15 * 8];
        denom += w;
#pragma unroll
        for (int i = 0; i < 8; ++i) acc[i] = fmaf(w, (float)h[i], acc[i]);
    }

    // combine the 4 edge slots (lane bits 4 and 5)
#pragma unroll
    for (int i = 0; i < 8; ++i) {
        acc[i] += __shfl_xor(acc[i], 16, 64);
        acc[i] += __shfl_xor(acc[i], 32, 64);
    }
    denom += __shfl_xor(denom, 16, 64);
    denom += __shfl_xor(denom, 32, 64);

    if (g == 0) {
        float inv = 1.0f / denom;
        float4 b0 = *(const float4*)&bias[l15 * 8];
        float4 b1 = *(const float4*)&bias[l15 * 8 + 4];
        float4 o0, o1;
        o0.x = fmaxf(fmaf(acc[0], inv, b0.x), 0.0f);
        o0.y = fmaxf(fmaf(acc[1], inv, b0.y), 0.0f);
        o0.z = fmaxf(fmaf(acc[2], inv, b0.z), 0.0f);
        o0.w = fmaxf(fmaf(acc[3], inv, b0.w), 0.0f);
        o1.x = fmaxf(fmaf(acc[4], inv, b1.x), 0.0f);
        o1.y = fmaxf(fmaf(acc[5], inv, b1.y), 0.0f);
        o1.z = fmaxf(fmaf(acc[6], inv, b1.z), 0.0f);
        o1.w = fmaxf(fmaf(acc[7], inv, b1.w), 0.0f);
        *(float4*)&Y[(size_t)v * 128 + l15 * 8] = o0;
        *(float4*)&Y[(size_t)v * 128 + l15 * 8 + 4] = o1;
    }
}

// ---------------------------------------------------------------------------
// BatchNorm stats / finalize / apply (apply only used for the last layer;
// layers 0-1 are applied inside the next gemm_attn's A-load).
// ---------------------------------------------------------------------------
__global__ __launch_bounds__(256) void bn_stats(const float* __restrict__ Y,
                                                float* __restrict__ partial) {
    __shared__ float red[256 * 8];    // 8 KB
    int tid = threadIdx.x;
    int rowlane = tid >> 5;           // 0..7
    int cg = tid & 31;                // col-group of 4
    float4 s = make_float4(0, 0, 0, 0);
    float4 qq = make_float4(0, 0, 0, 0);
    for (int i = blockIdx.x * 8 + rowlane; i < N_NODES; i += BN_NB * 8) {
        float4 v = *(const float4*)&Y[(size_t)i * 128 + cg * 4];
        s.x += v.x; s.y += v.y; s.z += v.z; s.w += v.w;
        qq.x = fmaf(v.x, v.x, qq.x);
        qq.y = fmaf(v.y, v.y, qq.y);
        qq.z = fmaf(v.z, v.z, qq.z);
        qq.w = fmaf(v.w, v.w, qq.w);
    }
    float* r = &red[tid * 8];
    r[0] = s.x; r[1] = s.y; r[2] = s.z; r[3] = s.w;
    r[4] = qq.x; r[5] = qq.y; r[6] = qq.z; r[7] = qq.w;
    __syncthreads();
    for (int off = 4; off > 0; off >>= 1) {
        if (rowlane < off) {
            float* o = &red[(tid + off * 32) * 8];
#pragma unroll
            for (int t = 0; t < 8; ++t) r[t] += o[t];
        }
        __syncthreads();
    }
    if (rowlane == 0) {
        *(float4*)&partial[(size_t)blockIdx.x * 256 + cg * 4] =
            make_float4(r[0], r[1], r[2], r[3]);
        *(float4*)&partial[(size_t)blockIdx.x * 256 + 128 + cg * 4] =
            make_float4(r[4], r[5], r[6], r[7]);
    }
}

__global__ __launch_bounds__(256) void bn_finalize(const float* __restrict__ partial,
                                                   const float* __restrict__ gamma,
                                                   const float* __restrict__ beta,
                                                   float* __restrict__ gb) {
    __shared__ float tot[256];
    int tid = threadIdx.x;
    float acc = 0.0f;
    for (int b = 0; b < BN_NB; ++b) acc += partial[(size_t)b * 256 + tid];
    tot[tid] = acc;
    __syncthreads();
    if (tid < 128) {
        const float invN = 1.0f / (float)N_NODES;
        float mu = tot[tid] * invN;
        float var = tot[128 + tid] * invN - mu * mu;
        float g = gamma[tid] * rsqrtf(var + BN_EPS);
        gb[tid] = g;
        gb[128 + tid] = beta[tid] - mu * g;
    }
}

__global__ __launch_bounds__(256) void bn_apply(const float* __restrict__ Y,
                                                const float* __restrict__ gb,
                                                float* __restrict__ out) {
    int idx = blockIdx.x * blockDim.x + threadIdx.x;
    if (idx >= N_NODES * 32) return;
    int row = idx >> 5;
    int c4 = (idx & 31) * 4;
    float4 v = *(const float4*)&Y[(size_t)row * 128 + c4];
    float4 g = *(const float4*)&gb[c4];
    float4 b = *(const float4*)&gb[128 + c4];
    v.x = fmaf(v.x, g.x, b.x);
    v.y = fmaf(v.y, g.y, b.y);
    v.z = fmaf(v.z, g.z, b.z);
    v.w = fmaf(v.w, g.w, b.w);
    *(float4*)&out[(size_t)row * 384 + c4] = v;
}

// ---------------------------------------------------------------------------
// driver
// ---------------------------------------------------------------------------
extern "C" void kernel_launch(void* const* d_in, const int* in_sizes, int n_in,
                              void* d_out, int out_size, void* d_ws, size_t ws_size,
                              hipStream_t stream) {
    const float* x      = (const float*)d_in[0];
    const int*   ei     = (const int*)d_in[1];   // [2, E] int32
    const float* Wall   = (const float*)d_in[2];
    const float* asrcs  = (const float*)d_in[3];
    const float* adsts  = (const float*)d_in[4];
    const float* biases = (const float*)d_in[5];
    const float* gammas = (const float*)d_in[6];
    const float* betas  = (const float*)d_in[7];
    float* out = (float*)d_out;

    // workspace layout
    unsigned short* Hh = (unsigned short*)d_ws;              // N*128 fp16
    float* Y       = (float*)(Hh + (size_t)N_NODES * 128);   // N*128 fp32
    float* Ssrc    = Y + (size_t)N_NODES * 128;
    float* Sdst    = Ssrc + N_NODES;
    float* bnpart  = Sdst + N_NODES;                         // 256*256
    float* gb      = bnpart + BN_NB * 256;                   // 256
    unsigned short* Wh = (unsigned short*)(gb + 256);        // 3*128*128 fp16 (16B aligned)
    // ---- zero zone (contiguous) ----
    int* deg       = (int*)(Wh + 3 * 128 * 128);             // 100000
    int* bucket_next = deg + N_NODES;                        // 8
    // ---- end zero zone ----
    int* row_ptr   = bucket_next + NBUCK;                    // 100001
    int* nextp     = row_ptr + (N_NODES + 1);                // 100000
    int* partials  = nextp + N_NODES;                        // 128
    int* csr_src   = partials + 128;                         // 1.7M
    int2* buckets  = (int2*)(csr_src + M_TOT + 2);           // 8*240000 int2

    const int ZERO_CNT = N_NODES + NBUCK;
    const int NB_EDGE = (M_TOT + EB_TPB - 1) / EB_TPB;       // 3321
    const int NB_PART = 2048;

    // ---- CSR build (bucketed, deg fused) + one-shot W convert ----
    zero_i32<<<(ZERO_CNT + 255) / 256, 256, 0, stream>>>(deg, ZERO_CNT);
    conv_w<<<192, 256, 0, stream>>>(Wall, Wh);
    bucket_edges<<<NB_EDGE, EB_TPB, 0, stream>>>(ei, bucket_next, buckets, deg);
    block_sums<<<SCAN_NB, 256, 0, stream>>>(deg, partials);
    scan_partials<<<1, 128, 0, stream>>>(partials, SCAN_NB, row_ptr);
    scan_write<<<SCAN_NB, 256, 0, stream>>>(deg, partials, row_ptr, nextp);
    scatter_b<<<NB_PART, 256, 0, stream>>>(buckets, bucket_next, nextp, csr_src);

    // ---- 3 GAT layers (BN apply of layer l-1 fused into gemm of layer l) ----
    for (int l = 0; l < 3; ++l) {
        const float* xin;
        int ldx;
        const float* gbl;
        float* outw;
        if (l == 0) { xin = x; ldx = 128; gbl = nullptr; outw = nullptr; }
        else        { xin = Y; ldx = 128; gbl = gb; outw = out + (size_t)(l - 1) * 128; }
        gemm_attn<<<(N_NODES + 63) / 64, 256, 0, stream>>>(
            xin, ldx, Wh + (size_t)l * 128 * 128,
            asrcs + l * 128, adsts + l * 128, gbl, outw, Hh, Ssrc, Sdst);
        aggregate<<<N_NODES / 4, 256, 0, stream>>>(
            Hh, row_ptr, csr_src, Ssrc, Sdst, biases + l * 128, Y);
        bn_stats<<<BN_NB, 256, 0, stream>>>(Y, bnpart);
        bn_finalize<<<1, 256, 0, stream>>>(bnpart, gammas + l * 128,
                                           betas + l * 128, gb);
    }
    // final layer's BN apply (no following gemm to fuse into)
    bn_apply<<<(N_NODES * 32 + 255) / 256, 256, 0, stream>>>(
        Y, gb, out + (size_t)2 * 128);
}

// Round 8
// 722.609 us; speedup vs baseline: 1.2124x; 1.0348x over previous
//
#include <hip/hip_runtime.h>
#include <math.h>

#define N_NODES 100000
#define N_EDGES 1600000
#define M_TOT   (N_EDGES + N_NODES)   // edges + self loops = 1,700,000
#define C_DIM   128
#define NEG_SLOPE 0.2f
#define BN_EPS 1e-5f

#define NBUCK 8
#define BUCK_NODES 12500
#define BUCK_CAP 240000

#define SCAN_NB 98                    // ceil(100000/1024)
#define HS_LD 136                     // LDS halves stride (272B, 16B-aligned)
#define EB_TPB 512                    // bucket_edges block size
#define BN_BANKS 64                   // banked BN accumulators

typedef _Float16 f16x8 __attribute__((ext_vector_type(8)));
typedef float f32x4 __attribute__((ext_vector_type(4)));

static __device__ __forceinline__ unsigned short f2h(float f) {
    _Float16 h = (_Float16)f;
    unsigned short u;
    __builtin_memcpy(&u, &h, 2);
    return u;
}
static __device__ __forceinline__ _Float16 f2h16(float f) { return (_Float16)f; }

// ---------------------------------------------------------------------------
// utility
// ---------------------------------------------------------------------------
__global__ void zero_i32(int* __restrict__ p, int n) {
    int i = blockIdx.x * blockDim.x + threadIdx.x;
    if (i < n) p[i] = 0;
}

// One-shot: convert all 3 W matrices to fp16, transposed to n-major:
// Wh[l][n][k] = (fp16) W[l][k][n].  32KB per layer -> L1/L2-resident in gemm.
__global__ __launch_bounds__(256) void conv_w(const float* __restrict__ Wall,
                                              unsigned short* __restrict__ Wh) {
    int i = blockIdx.x * 256 + threadIdx.x;   // coalesced read index
    if (i >= 3 * 128 * 128) return;
    int l = i >> 14;
    int r = i & 16383;
    int k = r >> 7;
    int n = r & 127;
    Wh[(size_t)l * 16384 + n * 128 + k] = f2h(Wall[i]);
}

// ---------------------------------------------------------------------------
// CSR build, XCD-partitioned bucket sort. Degree counting fused.
// Wave-ballot counting + LDS staging for coalesced bucket flushes.
// ---------------------------------------------------------------------------
__global__ __launch_bounds__(EB_TPB) void bucket_edges(const int* __restrict__ ei,
                                                       int* __restrict__ bucket_next,
                                                       int2* __restrict__ buckets,
                                                       int* __restrict__ deg) {
    __shared__ int2 stage[NBUCK * EB_TPB];   // 32 KB
    __shared__ int cnt[NBUCK];
    __shared__ int base[NBUCK];
    int tid = threadIdx.x;
    int lane = tid & 63;
    if (tid < NBUCK) cnt[tid] = 0;
    __syncthreads();

    int m = blockIdx.x * EB_TPB + tid;
    bool valid = (m < M_TOT);
    int src = 0, dst = 0, p = 0;
    if (valid) {
        if (m < N_EDGES) { src = ei[m]; dst = ei[N_EDGES + m]; }
        else             { src = m - N_EDGES; dst = src; }
        p = dst / BUCK_NODES;
        atomicAdd(&deg[dst], 1);
    }

    int myoff = 0;
#pragma unroll
    for (int b = 0; b < NBUCK; ++b) {
        unsigned long long mask = __ballot(valid && (p == b));
        if (mask) {
            int cntb = __popcll(mask);
            int leader = __ffsll((unsigned long long)mask) - 1;
            int wbase = 0;
            if (lane == leader) wbase = atomicAdd(&cnt[b], cntb);
            wbase = __shfl(wbase, leader, 64);
            if (valid && (p == b))
                myoff = wbase + __popcll(mask & ((1ull << lane) - 1ull));
        }
    }
    if (valid) stage[p * EB_TPB + myoff] = make_int2(src, dst);
    __syncthreads();

    if (tid < NBUCK) base[tid] = (cnt[tid] > 0) ? atomicAdd(&bucket_next[tid], cnt[tid]) : 0;
    __syncthreads();

#pragma unroll
    for (int b = 0; b < NBUCK; ++b) {
        int c = cnt[b];
        int2* dp = buckets + (size_t)b * BUCK_CAP + base[b];
        const int2* sp = &stage[b * EB_TPB];
        for (int i = tid; i < c; i += EB_TPB) dp[i] = sp[i];
    }
}

__global__ __launch_bounds__(256) void scatter_b(const int2* __restrict__ buckets,
                                                 const int* __restrict__ bucket_next,
                                                 int* __restrict__ nextp,
                                                 int* __restrict__ csr_src) {
    int p = blockIdx.x & 7;
    int chunk = blockIdx.x >> 3;
    int len = bucket_next[p];
    const int2* b = buckets + (size_t)p * BUCK_CAP;
    int stride = (gridDim.x >> 3) * 256;
    for (int i = chunk * 256 + threadIdx.x; i < len; i += stride) {
        int2 e = b[i];
        int pos = atomicAdd(&nextp[e.y], 1);
        csr_src[pos] = e.x;
    }
}

// ---------------------------------------------------------------------------
// prefix scan over deg -> row_ptr / nextp
// ---------------------------------------------------------------------------
__global__ __launch_bounds__(256) void block_sums(const int* __restrict__ deg,
                                                  int* __restrict__ partials) {
    __shared__ int lds[256];
    int base = blockIdx.x * 1024;
    int s = 0;
    for (int i = threadIdx.x; i < 1024; i += 256) {
        int idx = base + i;
        if (idx < N_NODES) s += deg[idx];
    }
    lds[threadIdx.x] = s;
    __syncthreads();
    for (int off = 128; off > 0; off >>= 1) {
        if (threadIdx.x < off) lds[threadIdx.x] += lds[threadIdx.x + off];
        __syncthreads();
    }
    if (threadIdx.x == 0) partials[blockIdx.x] = lds[0];
}

__global__ __launch_bounds__(128) void scan_partials(int* __restrict__ partials, int nb,
                                                     int* __restrict__ row_ptr) {
    __shared__ int lds[128];
    int tid = threadIdx.x;
    int v = (tid < nb) ? partials[tid] : 0;
    lds[tid] = v;
    __syncthreads();
    for (int off = 1; off < 128; off <<= 1) {
        int t = (tid >= off) ? lds[tid - off] : 0;
        __syncthreads();
        lds[tid] += t;
        __syncthreads();
    }
    if (tid < nb) partials[tid] = lds[tid] - v;   // exclusive
    if (tid == 0) row_ptr[N_NODES] = M_TOT;
}

__global__ __launch_bounds__(256) void scan_write(const int* __restrict__ deg,
                                                  const int* __restrict__ partials,
                                                  int* __restrict__ row_ptr,
                                                  int* __restrict__ nextp) {
    __shared__ int lds[256];
    int tid = threadIdx.x;
    int base = blockIdx.x * 1024;
    int i0 = base + tid * 4;
    int d[4];
#pragma unroll
    for (int t = 0; t < 4; ++t)
        d[t] = (i0 + t < N_NODES) ? deg[i0 + t] : 0;
    int tsum = d[0] + d[1] + d[2] + d[3];
    lds[tid] = tsum;
    __syncthreads();
    for (int off = 1; off < 256; off <<= 1) {
        int v = (tid >= off) ? lds[tid - off] : 0;
        __syncthreads();
        lds[tid] += v;
        __syncthreads();
    }
    int excl = lds[tid] - tsum;
    int run = partials[blockIdx.x] + excl;
#pragma unroll
    for (int t = 0; t < 4; ++t) {
        if (i0 + t < N_NODES) {
            row_ptr[i0 + t] = run;
            nextp[i0 + t]   = run;
            run += d[t];
        }
    }
}

// ---------------------------------------------------------------------------
// LDS-free-staging MFMA fp16 GEMM, 64-row tiles. A loaded directly from
// global, W from pre-converted fp16 Wh. BN apply of previous layer fused
// into the A load. Hh staged through LDS for coalesced stores.
// ---------------------------------------------------------------------------
__global__ __launch_bounds__(256, 4) void gemm_attn(
    const float* __restrict__ X, int ldx,
    const unsigned short* __restrict__ Wh,
    const float* __restrict__ a_src, const float* __restrict__ a_dst,
    const float* __restrict__ gbv,           // nullptr for layer 0
    float* __restrict__ outw,                // out slice of previous layer
    unsigned short* __restrict__ Hh, float* __restrict__ Ssrc,
    float* __restrict__ Sdst) {
    __shared__ unsigned short Hs[64 * HS_LD];   // 17 KB
    int tid = threadIdx.x;
    int wave = tid >> 6;
    int lane = tid & 63;
    int q = lane >> 4;
    int l15 = lane & 15;
    int wrow = wave * 16;
    int rbase = blockIdx.x * 64;

    int row0 = rbase + wrow + l15;
    bool ok0 = row0 < N_NODES;
    int r0c = ok0 ? row0 : (N_NODES - 1);

    f32x4 acc[8] = {};

#pragma unroll
    for (int ks = 0; ks < 128; ks += 32) {
        int k0 = ks + q * 8;
        float4 v0 = *(const float4*)&X[(size_t)r0c * ldx + k0];
        float4 v1 = *(const float4*)&X[(size_t)r0c * ldx + k0 + 4];
        if (gbv) {
            float4 g0 = *(const float4*)&gbv[k0];
            float4 g1 = *(const float4*)&gbv[k0 + 4];
            float4 b0 = *(const float4*)&gbv[128 + k0];
            float4 b1 = *(const float4*)&gbv[128 + k0 + 4];
            v0.x = fmaf(v0.x, g0.x, b0.x); v0.y = fmaf(v0.y, g0.y, b0.y);
            v0.z = fmaf(v0.z, g0.z, b0.z); v0.w = fmaf(v0.w, g0.w, b0.w);
            v1.x = fmaf(v1.x, g1.x, b1.x); v1.y = fmaf(v1.y, g1.y, b1.y);
            v1.z = fmaf(v1.z, g1.z, b1.z); v1.w = fmaf(v1.w, g1.w, b1.w);
            if (ok0) {
                *(float4*)&outw[(size_t)row0 * 384 + k0] = v0;
                *(float4*)&outw[(size_t)row0 * 384 + k0 + 4] = v1;
            }
        }
        f16x8 a;
        a[0] = f2h16(v0.x); a[1] = f2h16(v0.y); a[2] = f2h16(v0.z); a[3] = f2h16(v0.w);
        a[4] = f2h16(v1.x); a[5] = f2h16(v1.y); a[6] = f2h16(v1.z); a[7] = f2h16(v1.w);
#pragma unroll
        for (int c = 0; c < 8; ++c) {
            f16x8 b = *(const f16x8*)&Wh[(size_t)(c * 16 + l15) * 128 + k0];
            acc[c] = __builtin_amdgcn_mfma_f32_16x16x32_f16(a, b, acc[c], 0, 0, 0);
        }
    }

    // attention dot products (C/D layout: col=lane&15, row=(lane>>4)*4+reg)
    float avs[8], avd[8];
#pragma unroll
    for (int c = 0; c < 8; ++c) {
        avs[c] = a_src[c * 16 + l15];
        avd[c] = a_dst[c * 16 + l15];
    }
    float ps[4] = {0, 0, 0, 0}, pd[4] = {0, 0, 0, 0};
#pragma unroll
    for (int g = 0; g < 4; ++g) {
#pragma unroll
        for (int c = 0; c < 8; ++c) {
            float h = acc[c][g];
            ps[g] = fmaf(h, avs[c], ps[g]);
            pd[g] = fmaf(h, avd[c], pd[g]);
        }
    }
#pragma unroll
    for (int g = 0; g < 4; ++g) {
#pragma unroll
        for (int off = 1; off < 16; off <<= 1) {
            ps[g] += __shfl_xor(ps[g], off, 64);
            pd[g] += __shfl_xor(pd[g], off, 64);
        }
    }
    if (l15 == 0) {
#pragma unroll
        for (int g = 0; g < 4; ++g) {
            int row = rbase + wrow + q * 4 + g;
            if (row < N_NODES) {
                Ssrc[row] = ps[g];
                Sdst[row] = pd[g];
            }
        }
    }

    // Hh store via LDS staging -> coalesced 16B global stores.
#pragma unroll
    for (int c = 0; c < 8; ++c) {
#pragma unroll
        for (int g = 0; g < 4; ++g) {
            Hs[(wrow + q * 4 + g) * HS_LD + c * 16 + l15] = f2h(acc[c][g]);
        }
    }
    __syncthreads();
#pragma unroll
    for (int i = 0; i < 4; ++i) {
        int idx = i * 256 + tid;
        int lr = idx >> 4;            // 0..63
        int cg = (idx & 15) * 8;      // 0,8,...,120
        int grow = rbase + lr;
        if (grow < N_NODES) {
            *(f16x8*)&Hh[(size_t)grow * 128 + cg] =
                *(const f16x8*)&Hs[lr * HS_LD + cg];
        }
    }
}

// ---------------------------------------------------------------------------
// Per-node softmax + weighted aggregation, with BN stats fused.
// Proven cvt+fma payload (round-6 bit-exact); per-block BN reduction ->
// banked atomics (64 banks x 256 floats), replacing the bn_stats pass.
// ---------------------------------------------------------------------------
__global__ __launch_bounds__(256) void aggregate(
    const unsigned short* __restrict__ Hh, const int* __restrict__ row_ptr,
    const int* __restrict__ csr_src,
    const float* __restrict__ Ssrc, const float* __restrict__ Sdst,
    const float* __restrict__ bias, float* __restrict__ Y,
    float* __restrict__ bnsums) {
    __shared__ float bred[4][256];   // 4 KB
    int wave = threadIdx.x >> 6;
    int lane = threadIdx.x & 63;
    int g = lane >> 4;               // edge slot 0..3
    int l15 = lane & 15;             // channel group: ch = l15*8 + i
    int v = blockIdx.x * 4 + wave;
    int start = row_ptr[v];
    int end = row_ptr[v + 1];
    float sdv = Sdst[v];

    // anchor = self-loop score (exact softmax shift-invariance)
    float sself = Ssrc[v] + sdv;
    float m = (sself > 0.0f) ? sself : NEG_SLOPE * sself;

    float acc[8] = {0, 0, 0, 0, 0, 0, 0, 0};
    float denom = 0.0f;

    int j = start;
    for (; j + 16 <= end; j += 16) {
        int u0 = csr_src[j + g];
        int u1 = csr_src[j + 4 + g];
        int u2 = csr_src[j + 8 + g];
        int u3 = csr_src[j + 12 + g];
        float ss0 = Ssrc[u0];
        float ss1 = Ssrc[u1];
        float ss2 = Ssrc[u2];
        float ss3 = Ssrc[u3];
        f16x8 h0 = *(const f16x8*)&Hh[(size_t)u0 * 128 + l15 * 8];
        f16x8 h1 = *(const f16x8*)&Hh[(size_t)u1 * 128 + l15 * 8];
        f16x8 h2 = *(const f16x8*)&Hh[(size_t)u2 * 128 + l15 * 8];
        f16x8 h3 = *(const f16x8*)&Hh[(size_t)u3 * 128 + l15 * 8];
        float s0 = ss0 + sdv; s0 = (s0 > 0.0f) ? s0 : NEG_SLOPE * s0;
        float s1 = ss1 + sdv; s1 = (s1 > 0.0f) ? s1 : NEG_SLOPE * s1;
        float s2 = ss2 + sdv; s2 = (s2 > 0.0f) ? s2 : NEG_SLOPE * s2;
        float s3 = ss3 + sdv; s3 = (s3 > 0.0f) ? s3 : NEG_SLOPE * s3;
        float w0 = __expf(s0 - m);
        float w1 = __expf(s1 - m);
        float w2 = __expf(s2 - m);
        float w3 = __expf(s3 - m);
        denom += (w0 + w1) + (w2 + w3);
#pragma unroll
        for (int i = 0; i < 8; ++i) acc[i] = fmaf(w0, (float)h0[i], acc[i]);
#pragma unroll
        for (int i = 0; i < 8; ++i) acc[i] = fmaf(w1, (float)h1[i], acc[i]);
#pragma unroll
        for (int i = 0; i < 8; ++i) acc[i] = fmaf(w2, (float)h2[i], acc[i]);
#pragma unroll
        for (int i = 0; i < 8; ++i) acc[i] = fmaf(w3, (float)h3[i], acc[i]);
    }
    for (; j + 8 <= end; j += 8) {
        int u0 = csr_src[j + g];
        int u1 = csr_src[j + 4 + g];
        float ss0 = Ssrc[u0];
        float ss1 = Ssrc[u1];
        f16x8 h0 = *(const f16x8*)&Hh[(size_t)u0 * 128 + l15 * 8];
        f16x8 h1 = *(const f16x8*)&Hh[(size_t)u1 * 128 + l15 * 8];
        float s0 = ss0 + sdv; s0 = (s0 > 0.0f) ? s0 : NEG_SLOPE * s0;
        float s1 = ss1 + sdv; s1 = (s1 > 0.0f) ? s1 : NEG_SLOPE * s1;
        float w0 = __expf(s0 - m);
        float w1 = __expf(s1 - m);
        denom += w0 + w1;
#pragma unroll
        for (int i = 0; i < 8; ++i) acc[i] = fmaf(w0, (float)h0[i], acc[i]);
#pragma unroll
        for (int i = 0; i < 8; ++i) acc[i] = fmaf(w1, (float)h1[i], acc[i]);
    }
    for (; j < end; j += 4) {
        int je = j + g;
        bool ok = (je < end);
        int u = ok ? csr_src[je] : v;
        float s = Ssrc[u] + sdv; s = (s > 0.0f) ? s : NEG_SLOPE * s;
        float w = ok ? __expf(s - m) : 0.0f;
        f16x8 h = *(const f16x8*)&Hh[(size_t)u * 128 + l15 * 8];
        denom += w;
#pragma unroll
        for (int i = 0; i < 8; ++i) acc[i] = fmaf(w, (float)h[i], acc[i]);
    }

    // combine the 4 edge slots (lane bits 4 and 5)
#pragma unroll
    for (int i = 0; i < 8; ++i) {
        acc[i] += __shfl_xor(acc[i], 16, 64);
        acc[i] += __shfl_xor(acc[i], 32, 64);
    }
    denom += __shfl_xor(denom, 16, 64);
    denom += __shfl_xor(denom, 32, 64);

    if (g == 0) {
        float inv = 1.0f / denom;
        float4 b0 = *(const float4*)&bias[l15 * 8];
        float4 b1 = *(const float4*)&bias[l15 * 8 + 4];
        float bb[8] = {b0.x, b0.y, b0.z, b0.w, b1.x, b1.y, b1.z, b1.w};
        float ov[8];
#pragma unroll
        for (int i = 0; i < 8; ++i)
            ov[i] = fmaxf(fmaf(acc[i], inv, bb[i]), 0.0f);
        *(float4*)&Y[(size_t)v * 128 + l15 * 8] =
            make_float4(ov[0], ov[1], ov[2], ov[3]);
        *(float4*)&Y[(size_t)v * 128 + l15 * 8 + 4] =
            make_float4(ov[4], ov[5], ov[6], ov[7]);
        // BN stats: per-wave slice of sums and squares
        int c = l15 * 8;
#pragma unroll
        for (int i = 0; i < 8; ++i) {
            bred[wave][c + i] = ov[i];
            bred[wave][128 + c + i] = ov[i] * ov[i];
        }
    }
    __syncthreads();
    int tid = threadIdx.x;
    float t = bred[0][tid] + bred[1][tid] + bred[2][tid] + bred[3][tid];
    atomicAdd(&bnsums[(blockIdx.x & (BN_BANKS - 1)) * 256 + tid], t);
}

// ---------------------------------------------------------------------------
// BatchNorm finalize: sum the banked accumulators, compute gb, re-zero the
// banks for the next layer. bn_apply only for the last layer.
// ---------------------------------------------------------------------------
__global__ __launch_bounds__(256) void bn_finalize(float* __restrict__ bnsums,
                                                   const float* __restrict__ gamma,
                                                   const float* __restrict__ beta,
                                                   float* __restrict__ gb) {
    __shared__ float tot[256];
    int tid = threadIdx.x;
    float acc = 0.0f;
    for (int b = 0; b < BN_BANKS; ++b) acc += bnsums[(size_t)b * 256 + tid];
    for (int b = 0; b < BN_BANKS; ++b) bnsums[(size_t)b * 256 + tid] = 0.0f;
    tot[tid] = acc;
    __syncthreads();
    if (tid < 128) {
        const float invN = 1.0f / (float)N_NODES;
        float mu = tot[tid] * invN;
        float var = tot[128 + tid] * invN - mu * mu;
        float g = gamma[tid] * rsqrtf(var + BN_EPS);
        gb[tid] = g;
        gb[128 + tid] = beta[tid] - mu * g;
    }
}

__global__ __launch_bounds__(256) void bn_apply(const float* __restrict__ Y,
                                                const float* __restrict__ gb,
                                                float* __restrict__ out) {
    int idx = blockIdx.x * blockDim.x + threadIdx.x;
    if (idx >= N_NODES * 32) return;
    int row = idx >> 5;
    int c4 = (idx & 31) * 4;
    float4 v = *(const float4*)&Y[(size_t)row * 128 + c4];
    float4 g = *(const float4*)&gb[c4];
    float4 b = *(const float4*)&gb[128 + c4];
    v.x = fmaf(v.x, g.x, b.x);
    v.y = fmaf(v.y, g.y, b.y);
    v.z = fmaf(v.z, g.z, b.z);
    v.w = fmaf(v.w, g.w, b.w);
    *(float4*)&out[(size_t)row * 384 + c4] = v;
}

// ---------------------------------------------------------------------------
// driver
// ---------------------------------------------------------------------------
extern "C" void kernel_launch(void* const* d_in, const int* in_sizes, int n_in,
                              void* d_out, int out_size, void* d_ws, size_t ws_size,
                              hipStream_t stream) {
    const float* x      = (const float*)d_in[0];
    const int*   ei     = (const int*)d_in[1];   // [2, E] int32
    const float* Wall   = (const float*)d_in[2];
    const float* asrcs  = (const float*)d_in[3];
    const float* adsts  = (const float*)d_in[4];
    const float* biases = (const float*)d_in[5];
    const float* gammas = (const float*)d_in[6];
    const float* betas  = (const float*)d_in[7];
    float* out = (float*)d_out;

    // workspace layout
    unsigned short* Hh = (unsigned short*)d_ws;              // N*128 fp16
    float* Y       = (float*)(Hh + (size_t)N_NODES * 128);   // N*128 fp32
    float* Ssrc    = Y + (size_t)N_NODES * 128;
    float* Sdst    = Ssrc + N_NODES;
    float* gb      = Sdst + N_NODES;                         // 256
    unsigned short* Wh = (unsigned short*)(gb + 256);        // 3*128*128 fp16
    // ---- zero zone (contiguous) ----
    int* deg       = (int*)(Wh + 3 * 128 * 128);             // 100000
    int* bucket_next = deg + N_NODES;                        // 8
    float* bnsums  = (float*)(bucket_next + NBUCK);          // 64*256
    // ---- end zero zone ----
    int* row_ptr   = (int*)(bnsums + BN_BANKS * 256);        // 100001
    int* nextp     = row_ptr + (N_NODES + 1);                // 100000
    int* partials  = nextp + N_NODES;                        // 128
    int* csr_src   = partials + 128;                         // 1.7M
    int2* buckets  = (int2*)(csr_src + M_TOT + 2);           // 8*240000 int2

    const int ZERO_CNT = N_NODES + NBUCK + BN_BANKS * 256;
    const int NB_EDGE = (M_TOT + EB_TPB - 1) / EB_TPB;       // 3321
    const int NB_PART = 2048;

    // ---- CSR build (bucketed, deg fused) + one-shot W convert ----
    zero_i32<<<(ZERO_CNT + 255) / 256, 256, 0, stream>>>(deg, ZERO_CNT);
    conv_w<<<192, 256, 0, stream>>>(Wall, Wh);
    bucket_edges<<<NB_EDGE, EB_TPB, 0, stream>>>(ei, bucket_next, buckets, deg);
    block_sums<<<SCAN_NB, 256, 0, stream>>>(deg, partials);
    scan_partials<<<1, 128, 0, stream>>>(partials, SCAN_NB, row_ptr);
    scan_write<<<SCAN_NB, 256, 0, stream>>>(deg, partials, row_ptr, nextp);
    scatter_b<<<NB_PART, 256, 0, stream>>>(buckets, bucket_next, nextp, csr_src);

    // ---- 3 GAT layers (BN apply of layer l-1 fused into gemm of layer l;
    //      BN stats fused into aggregate) ----
    for (int l = 0; l < 3; ++l) {
        const float* xin;
        int ldx;
        const float* gbl;
        float* outw;
        if (l == 0) { xin = x; ldx = 128; gbl = nullptr; outw = nullptr; }
        else        { xin = Y; ldx = 128; gbl = gb; outw = out + (size_t)(l - 1) * 128; }
        gemm_attn<<<(N_NODES + 63) / 64, 256, 0, stream>>>(
            xin, ldx, Wh + (size_t)l * 128 * 128,
            asrcs + l * 128, adsts + l * 128, gbl, outw, Hh, Ssrc, Sdst);
        aggregate<<<N_NODES / 4, 256, 0, stream>>>(
            Hh, row_ptr, csr_src, Ssrc, Sdst, biases + l * 128, Y, bnsums);
        bn_finalize<<<1, 256, 0, stream>>>(bnsums, gammas + l * 128,
                                           betas + l * 128, gb);
    }
    // final layer's BN apply (no following gemm to fuse into)
    bn_apply<<<(N_NODES * 32 + 255) / 256, 256, 0, stream>>>(
        Y, gb, out + (size_t)2 * 128);
}

// Round 9
// 699.228 us; speedup vs baseline: 1.2529x; 1.0334x over previous
//
#include <hip/hip_runtime.h>
#include <math.h>

#define N_NODES 100000
#define N_EDGES 1600000
#define M_TOT   (N_EDGES + N_NODES)   // edges + self loops = 1,700,000
#define C_DIM   128
#define NEG_SLOPE 0.2f
#define BN_EPS 1e-5f

#define NBUCK 8
#define BUCK_NODES 12500
#define BUCK_CAP 240000

#define SCAN_NB 98                    // ceil(100000/1024)
#define HS_LD 136                     // LDS halves stride (272B, 16B-aligned)
#define EB_TPB 512                    // bucket_edges block size
#define BN_BANKS 64                   // banked BN accumulators

typedef _Float16 f16x8 __attribute__((ext_vector_type(8)));
typedef float f32x4 __attribute__((ext_vector_type(4)));

static __device__ __forceinline__ unsigned short f2h(float f) {
    _Float16 h = (_Float16)f;
    unsigned short u;
    __builtin_memcpy(&u, &h, 2);
    return u;
}
static __device__ __forceinline__ _Float16 f2h16(float f) { return (_Float16)f; }

// ---------------------------------------------------------------------------
// merged: zero the zero-zone + one-shot W fp16 transpose (Wh[l][n][k])
// ---------------------------------------------------------------------------
__global__ __launch_bounds__(256) void zero_conv(const float* __restrict__ Wall,
                                                 unsigned short* __restrict__ Wh,
                                                 int* __restrict__ zp, int zn) {
    int i = blockIdx.x * 256 + threadIdx.x;
    if (i < 3 * 128 * 128) {
        int l = i >> 14;
        int r = i & 16383;
        int k = r >> 7;
        int n = r & 127;
        Wh[(size_t)l * 16384 + n * 128 + k] = f2h(Wall[i]);
    }
    if (i < zn) zp[i] = 0;
}

// ---------------------------------------------------------------------------
// CSR build, XCD-partitioned bucket sort. Degree counting fused.
// Wave-ballot counting + LDS staging for coalesced bucket flushes.
// ---------------------------------------------------------------------------
__global__ __launch_bounds__(EB_TPB) void bucket_edges(const int* __restrict__ ei,
                                                       int* __restrict__ bucket_next,
                                                       int2* __restrict__ buckets,
                                                       int* __restrict__ deg) {
    __shared__ int2 stage[NBUCK * EB_TPB];   // 32 KB
    __shared__ int cnt[NBUCK];
    __shared__ int base[NBUCK];
    int tid = threadIdx.x;
    int lane = tid & 63;
    if (tid < NBUCK) cnt[tid] = 0;
    __syncthreads();

    int m = blockIdx.x * EB_TPB + tid;
    bool valid = (m < M_TOT);
    int src = 0, dst = 0, p = 0;
    if (valid) {
        if (m < N_EDGES) { src = ei[m]; dst = ei[N_EDGES + m]; }
        else             { src = m - N_EDGES; dst = src; }
        p = dst / BUCK_NODES;
        atomicAdd(&deg[dst], 1);
    }

    int myoff = 0;
#pragma unroll
    for (int b = 0; b < NBUCK; ++b) {
        unsigned long long mask = __ballot(valid && (p == b));
        if (mask) {
            int cntb = __popcll(mask);
            int leader = __ffsll((unsigned long long)mask) - 1;
            int wbase = 0;
            if (lane == leader) wbase = atomicAdd(&cnt[b], cntb);
            wbase = __shfl(wbase, leader, 64);
            if (valid && (p == b))
                myoff = wbase + __popcll(mask & ((1ull << lane) - 1ull));
        }
    }
    if (valid) stage[p * EB_TPB + myoff] = make_int2(src, dst);
    __syncthreads();

    if (tid < NBUCK) base[tid] = (cnt[tid] > 0) ? atomicAdd(&bucket_next[tid], cnt[tid]) : 0;
    __syncthreads();

#pragma unroll
    for (int b = 0; b < NBUCK; ++b) {
        int c = cnt[b];
        int2* dp = buckets + (size_t)b * BUCK_CAP + base[b];
        const int2* sp = &stage[b * EB_TPB];
        for (int i = tid; i < c; i += EB_TPB) dp[i] = sp[i];
    }
}

__global__ __launch_bounds__(256) void scatter_b(const int2* __restrict__ buckets,
                                                 const int* __restrict__ bucket_next,
                                                 int* __restrict__ nextp,
                                                 int* __restrict__ csr_src) {
    int p = blockIdx.x & 7;
    int chunk = blockIdx.x >> 3;
    int len = bucket_next[p];
    const int2* b = buckets + (size_t)p * BUCK_CAP;
    int stride = (gridDim.x >> 3) * 256;
    for (int i = chunk * 256 + threadIdx.x; i < len; i += stride) {
        int2 e = b[i];
        int pos = atomicAdd(&nextp[e.y], 1);
        csr_src[pos] = e.x;
    }
}

// ---------------------------------------------------------------------------
// prefix scan over deg -> row_ptr / nextp
// ---------------------------------------------------------------------------
__global__ __launch_bounds__(256) void block_sums(const int* __restrict__ deg,
                                                  int* __restrict__ partials) {
    __shared__ int lds[256];
    int base = blockIdx.x * 1024;
    int s = 0;
    for (int i = threadIdx.x; i < 1024; i += 256) {
        int idx = base + i;
        if (idx < N_NODES) s += deg[idx];
    }
    lds[threadIdx.x] = s;
    __syncthreads();
    for (int off = 128; off > 0; off >>= 1) {
        if (threadIdx.x < off) lds[threadIdx.x] += lds[threadIdx.x + off];
        __syncthreads();
    }
    if (threadIdx.x == 0) partials[blockIdx.x] = lds[0];
}

__global__ __launch_bounds__(128) void scan_partials(int* __restrict__ partials, int nb,
                                                     int* __restrict__ row_ptr) {
    __shared__ int lds[128];
    int tid = threadIdx.x;
    int v = (tid < nb) ? partials[tid] : 0;
    lds[tid] = v;
    __syncthreads();
    for (int off = 1; off < 128; off <<= 1) {
        int t = (tid >= off) ? lds[tid - off] : 0;
        __syncthreads();
        lds[tid] += t;
        __syncthreads();
    }
    if (tid < nb) partials[tid] = lds[tid] - v;   // exclusive
    if (tid == 0) row_ptr[N_NODES] = M_TOT;
}

__global__ __launch_bounds__(256) void scan_write(const int* __restrict__ deg,
                                                  const int* __restrict__ partials,
                                                  int* __restrict__ row_ptr,
                                                  int* __restrict__ nextp) {
    __shared__ int lds[256];
    int tid = threadIdx.x;
    int base = blockIdx.x * 1024;
    int i0 = base + tid * 4;
    int d[4];
#pragma unroll
    for (int t = 0; t < 4; ++t)
        d[t] = (i0 + t < N_NODES) ? deg[i0 + t] : 0;
    int tsum = d[0] + d[1] + d[2] + d[3];
    lds[tid] = tsum;
    __syncthreads();
    for (int off = 1; off < 256; off <<= 1) {
        int v = (tid >= off) ? lds[tid - off] : 0;
        __syncthreads();
        lds[tid] += v;
        __syncthreads();
    }
    int excl = lds[tid] - tsum;
    int run = partials[blockIdx.x] + excl;
#pragma unroll
    for (int t = 0; t < 4; ++t) {
        if (i0 + t < N_NODES) {
            row_ptr[i0 + t] = run;
            nextp[i0 + t]   = run;
            run += d[t];
        }
    }
}

// ---------------------------------------------------------------------------
// LDS-free-staging MFMA fp16 GEMM, 64-row tiles. A read either from fp32 x
// (layer 0) or fp16 Yh (layers >= 1, with fused BN apply + out-slice store).
// W from pre-converted fp16 Wh. Hh staged through LDS for coalesced stores.
// ---------------------------------------------------------------------------
__global__ __launch_bounds__(256, 4) void gemm_attn(
    const float* __restrict__ Xf,            // fp32 input (layer 0) or null
    const unsigned short* __restrict__ Xh,   // fp16 Yh (layers >= 1) or null
    const unsigned short* __restrict__ Wh,
    const float* __restrict__ a_src, const float* __restrict__ a_dst,
    const float* __restrict__ gbv,           // nullptr for layer 0
    float* __restrict__ outw,                // out slice of previous layer
    unsigned short* __restrict__ Hh, float* __restrict__ Ssrc,
    float* __restrict__ Sdst) {
    __shared__ unsigned short Hs[64 * HS_LD];   // 17 KB
    int tid = threadIdx.x;
    int wave = tid >> 6;
    int lane = tid & 63;
    int q = lane >> 4;
    int l15 = lane & 15;
    int wrow = wave * 16;
    int rbase = blockIdx.x * 64;

    int row0 = rbase + wrow + l15;
    bool ok0 = row0 < N_NODES;
    int r0c = ok0 ? row0 : (N_NODES - 1);

    f32x4 acc[8] = {};

#pragma unroll
    for (int ks = 0; ks < 128; ks += 32) {
        int k0 = ks + q * 8;
        f16x8 a;
        if (Xh) {
            // fp16 Yh path with fused BN apply of the previous layer
            f16x8 hv = *(const f16x8*)&Xh[(size_t)r0c * 128 + k0];
            float4 g0 = *(const float4*)&gbv[k0];
            float4 g1 = *(const float4*)&gbv[k0 + 4];
            float4 b0 = *(const float4*)&gbv[128 + k0];
            float4 b1 = *(const float4*)&gbv[128 + k0 + 4];
            float vv[8];
            vv[0] = fmaf((float)hv[0], g0.x, b0.x);
            vv[1] = fmaf((float)hv[1], g0.y, b0.y);
            vv[2] = fmaf((float)hv[2], g0.z, b0.z);
            vv[3] = fmaf((float)hv[3], g0.w, b0.w);
            vv[4] = fmaf((float)hv[4], g1.x, b1.x);
            vv[5] = fmaf((float)hv[5], g1.y, b1.y);
            vv[6] = fmaf((float)hv[6], g1.z, b1.z);
            vv[7] = fmaf((float)hv[7], g1.w, b1.w);
            if (ok0) {
                *(float4*)&outw[(size_t)row0 * 384 + k0] =
                    make_float4(vv[0], vv[1], vv[2], vv[3]);
                *(float4*)&outw[(size_t)row0 * 384 + k0 + 4] =
                    make_float4(vv[4], vv[5], vv[6], vv[7]);
            }
#pragma unroll
            for (int i = 0; i < 8; ++i) a[i] = f2h16(vv[i]);
        } else {
            float4 v0 = *(const float4*)&Xf[(size_t)r0c * 128 + k0];
            float4 v1 = *(const float4*)&Xf[(size_t)r0c * 128 + k0 + 4];
            a[0] = f2h16(v0.x); a[1] = f2h16(v0.y); a[2] = f2h16(v0.z); a[3] = f2h16(v0.w);
            a[4] = f2h16(v1.x); a[5] = f2h16(v1.y); a[6] = f2h16(v1.z); a[7] = f2h16(v1.w);
        }
#pragma unroll
        for (int c = 0; c < 8; ++c) {
            f16x8 b = *(const f16x8*)&Wh[(size_t)(c * 16 + l15) * 128 + k0];
            acc[c] = __builtin_amdgcn_mfma_f32_16x16x32_f16(a, b, acc[c], 0, 0, 0);
        }
    }

    // attention dot products (C/D layout: col=lane&15, row=(lane>>4)*4+reg)
    float avs[8], avd[8];
#pragma unroll
    for (int c = 0; c < 8; ++c) {
        avs[c] = a_src[c * 16 + l15];
        avd[c] = a_dst[c * 16 + l15];
    }
    float ps[4] = {0, 0, 0, 0}, pd[4] = {0, 0, 0, 0};
#pragma unroll
    for (int g = 0; g < 4; ++g) {
#pragma unroll
        for (int c = 0; c < 8; ++c) {
            float h = acc[c][g];
            ps[g] = fmaf(h, avs[c], ps[g]);
            pd[g] = fmaf(h, avd[c], pd[g]);
        }
    }
#pragma unroll
    for (int g = 0; g < 4; ++g) {
#pragma unroll
        for (int off = 1; off < 16; off <<= 1) {
            ps[g] += __shfl_xor(ps[g], off, 64);
            pd[g] += __shfl_xor(pd[g], off, 64);
        }
    }
    if (l15 == 0) {
#pragma unroll
        for (int g = 0; g < 4; ++g) {
            int row = rbase + wrow + q * 4 + g;
            if (row < N_NODES) {
                Ssrc[row] = ps[g];
                Sdst[row] = pd[g];
            }
        }
    }

    // Hh store via LDS staging -> coalesced 16B global stores.
#pragma unroll
    for (int c = 0; c < 8; ++c) {
#pragma unroll
        for (int g = 0; g < 4; ++g) {
            Hs[(wrow + q * 4 + g) * HS_LD + c * 16 + l15] = f2h(acc[c][g]);
        }
    }
    __syncthreads();
#pragma unroll
    for (int i = 0; i < 4; ++i) {
        int idx = i * 256 + tid;
        int lr = idx >> 4;            // 0..63
        int cg = (idx & 15) * 8;      // 0,8,...,120
        int grow = rbase + lr;
        if (grow < N_NODES) {
            *(f16x8*)&Hh[(size_t)grow * 128 + cg] =
                *(const f16x8*)&Hs[lr * HS_LD + cg];
        }
    }
}

// ---------------------------------------------------------------------------
// Per-node softmax + weighted aggregation, with BN stats fused.
// Output Y stored as fp16 (consumers convert to fp16 anyway / tolerate it);
// BN stats accumulate from the fp32 registers (pre-rounding).
// ---------------------------------------------------------------------------
__global__ __launch_bounds__(256) void aggregate(
    const unsigned short* __restrict__ Hh, const int* __restrict__ row_ptr,
    const int* __restrict__ csr_src,
    const float* __restrict__ Ssrc, const float* __restrict__ Sdst,
    const float* __restrict__ bias, unsigned short* __restrict__ Yh,
    float* __restrict__ bnsums) {
    __shared__ float bred[4][256];   // 4 KB
    int wave = threadIdx.x >> 6;
    int lane = threadIdx.x & 63;
    int g = lane >> 4;               // edge slot 0..3
    int l15 = lane & 15;             // channel group: ch = l15*8 + i
    int v = blockIdx.x * 4 + wave;
    int start = row_ptr[v];
    int end = row_ptr[v + 1];
    float sdv = Sdst[v];

    // anchor = self-loop score (exact softmax shift-invariance)
    float sself = Ssrc[v] + sdv;
    float m = (sself > 0.0f) ? sself : NEG_SLOPE * sself;

    float acc[8] = {0, 0, 0, 0, 0, 0, 0, 0};
    float denom = 0.0f;

    int j = start;
    for (; j + 16 <= end; j += 16) {
        int u0 = csr_src[j + g];
        int u1 = csr_src[j + 4 + g];
        int u2 = csr_src[j + 8 + g];
        int u3 = csr_src[j + 12 + g];
        float ss0 = Ssrc[u0];
        float ss1 = Ssrc[u1];
        float ss2 = Ssrc[u2];
        float ss3 = Ssrc[u3];
        f16x8 h0 = *(const f16x8*)&Hh[(size_t)u0 * 128 + l15 * 8];
        f16x8 h1 = *(const f16x8*)&Hh[(size_t)u1 * 128 + l15 * 8];
        f16x8 h2 = *(const f16x8*)&Hh[(size_t)u2 * 128 + l15 * 8];
        f16x8 h3 = *(const f16x8*)&Hh[(size_t)u3 * 128 + l15 * 8];
        float s0 = ss0 + sdv; s0 = (s0 > 0.0f) ? s0 : NEG_SLOPE * s0;
        float s1 = ss1 + sdv; s1 = (s1 > 0.0f) ? s1 : NEG_SLOPE * s1;
        float s2 = ss2 + sdv; s2 = (s2 > 0.0f) ? s2 : NEG_SLOPE * s2;
        float s3 = ss3 + sdv; s3 = (s3 > 0.0f) ? s3 : NEG_SLOPE * s3;
        float w0 = __expf(s0 - m);
        float w1 = __expf(s1 - m);
        float w2 = __expf(s2 - m);
        float w3 = __expf(s3 - m);
        denom += (w0 + w1) + (w2 + w3);
#pragma unroll
        for (int i = 0; i < 8; ++i) acc[i] = fmaf(w0, (float)h0[i], acc[i]);
#pragma unroll
        for (int i = 0; i < 8; ++i) acc[i] = fmaf(w1, (float)h1[i], acc[i]);
#pragma unroll
        for (int i = 0; i < 8; ++i) acc[i] = fmaf(w2, (float)h2[i], acc[i]);
#pragma unroll
        for (int i = 0; i < 8; ++i) acc[i] = fmaf(w3, (float)h3[i], acc[i]);
    }
    for (; j + 8 <= end; j += 8) {
        int u0 = csr_src[j + g];
        int u1 = csr_src[j + 4 + g];
        float ss0 = Ssrc[u0];
        float ss1 = Ssrc[u1];
        f16x8 h0 = *(const f16x8*)&Hh[(size_t)u0 * 128 + l15 * 8];
        f16x8 h1 = *(const f16x8*)&Hh[(size_t)u1 * 128 + l15 * 8];
        float s0 = ss0 + sdv; s0 = (s0 > 0.0f) ? s0 : NEG_SLOPE * s0;
        float s1 = ss1 + sdv; s1 = (s1 > 0.0f) ? s1 : NEG_SLOPE * s1;
        float w0 = __expf(s0 - m);
        float w1 = __expf(s1 - m);
        denom += w0 + w1;
#pragma unroll
        for (int i = 0; i < 8; ++i) acc[i] = fmaf(w0, (float)h0[i], acc[i]);
#pragma unroll
        for (int i = 0; i < 8; ++i) acc[i] = fmaf(w1, (float)h1[i], acc[i]);
    }
    for (; j < end; j += 4) {
        int je = j + g;
        bool ok = (je < end);
        int u = ok ? csr_src[je] : v;
        float s = Ssrc[u] + sdv; s = (s > 0.0f) ? s : NEG_SLOPE * s;
        float w = ok ? __expf(s - m) : 0.0f;
        f16x8 h = *(const f16x8*)&Hh[(size_t)u * 128 + l15 * 8];
        denom += w;
#pragma unroll
        for (int i = 0; i < 8; ++i) acc[i] = fmaf(w, (float)h[i], acc[i]);
    }

    // combine the 4 edge slots (lane bits 4 and 5)
#pragma unroll
    for (int i = 0; i < 8; ++i) {
        acc[i] += __shfl_xor(acc[i], 16, 64);
        acc[i] += __shfl_xor(acc[i], 32, 64);
    }
    denom += __shfl_xor(denom, 16, 64);
    denom += __shfl_xor(denom, 32, 64);

    if (g == 0) {
        float inv = 1.0f / denom;
        float4 b0 = *(const float4*)&bias[l15 * 8];
        float4 b1 = *(const float4*)&bias[l15 * 8 + 4];
        float bb[8] = {b0.x, b0.y, b0.z, b0.w, b1.x, b1.y, b1.z, b1.w};
        float ov[8];
        f16x8 yo;
#pragma unroll
        for (int i = 0; i < 8; ++i) {
            ov[i] = fmaxf(fmaf(acc[i], inv, bb[i]), 0.0f);
            yo[i] = f2h16(ov[i]);
        }
        *(f16x8*)&Yh[(size_t)v * 128 + l15 * 8] = yo;
        // BN stats: per-wave slice of sums and squares (fp32, pre-rounding)
        int c = l15 * 8;
#pragma unroll
        for (int i = 0; i < 8; ++i) {
            bred[wave][c + i] = ov[i];
            bred[wave][128 + c + i] = ov[i] * ov[i];
        }
    }
    __syncthreads();
    int tid = threadIdx.x;
    float t = bred[0][tid] + bred[1][tid] + bred[2][tid] + bred[3][tid];
    atomicAdd(&bnsums[(blockIdx.x & (BN_BANKS - 1)) * 256 + tid], t);
}

// ---------------------------------------------------------------------------
// BatchNorm finalize: sum the banked accumulators, compute gb, re-zero the
// banks for the next layer. bn_apply only for the last layer (fp16 Yh in).
// ---------------------------------------------------------------------------
__global__ __launch_bounds__(256) void bn_finalize(float* __restrict__ bnsums,
                                                   const float* __restrict__ gamma,
                                                   const float* __restrict__ beta,
                                                   float* __restrict__ gb) {
    __shared__ float tot[256];
    int tid = threadIdx.x;
    float acc = 0.0f;
    for (int b = 0; b < BN_BANKS; ++b) acc += bnsums[(size_t)b * 256 + tid];
    for (int b = 0; b < BN_BANKS; ++b) bnsums[(size_t)b * 256 + tid] = 0.0f;
    tot[tid] = acc;
    __syncthreads();
    if (tid < 128) {
        const float invN = 1.0f / (float)N_NODES;
        float mu = tot[tid] * invN;
        float var = tot[128 + tid] * invN - mu * mu;
        float g = gamma[tid] * rsqrtf(var + BN_EPS);
        gb[tid] = g;
        gb[128 + tid] = beta[tid] - mu * g;
    }
}

__global__ __launch_bounds__(256) void bn_apply(const unsigned short* __restrict__ Yh,
                                                const float* __restrict__ gb,
                                                float* __restrict__ out) {
    int idx = blockIdx.x * blockDim.x + threadIdx.x;
    if (idx >= N_NODES * 16) return;
    int row = idx >> 4;
    int c8 = (idx & 15) * 8;
    f16x8 hv = *(const f16x8*)&Yh[(size_t)row * 128 + c8];
    float4 g0 = *(const float4*)&gb[c8];
    float4 g1 = *(const float4*)&gb[c8 + 4];
    float4 b0 = *(const float4*)&gb[128 + c8];
    float4 b1 = *(const float4*)&gb[128 + c8 + 4];
    float4 o0, o1;
    o0.x = fmaf((float)hv[0], g0.x, b0.x);
    o0.y = fmaf((float)hv[1], g0.y, b0.y);
    o0.z = fmaf((float)hv[2], g0.z, b0.z);
    o0.w = fmaf((float)hv[3], g0.w, b0.w);
    o1.x = fmaf((float)hv[4], g1.x, b1.x);
    o1.y = fmaf((float)hv[5], g1.y, b1.y);
    o1.z = fmaf((float)hv[6], g1.z, b1.z);
    o1.w = fmaf((float)hv[7], g1.w, b1.w);
    *(float4*)&out[(size_t)row * 384 + c8] = o0;
    *(float4*)&out[(size_t)row * 384 + c8 + 4] = o1;
}

// ---------------------------------------------------------------------------
// driver
// ---------------------------------------------------------------------------
extern "C" void kernel_launch(void* const* d_in, const int* in_sizes, int n_in,
                              void* d_out, int out_size, void* d_ws, size_t ws_size,
                              hipStream_t stream) {
    const float* x      = (const float*)d_in[0];
    const int*   ei     = (const int*)d_in[1];   // [2, E] int32
    const float* Wall   = (const float*)d_in[2];
    const float* asrcs  = (const float*)d_in[3];
    const float* adsts  = (const float*)d_in[4];
    const float* biases = (const float*)d_in[5];
    const float* gammas = (const float*)d_in[6];
    const float* betas  = (const float*)d_in[7];
    float* out = (float*)d_out;

    // workspace layout
    unsigned short* Hh = (unsigned short*)d_ws;              // N*128 fp16
    unsigned short* Yh = Hh + (size_t)N_NODES * 128;         // N*128 fp16
    float* Ssrc    = (float*)(Yh + (size_t)N_NODES * 128);
    float* Sdst    = Ssrc + N_NODES;
    float* gb      = Sdst + N_NODES;                         // 256
    unsigned short* Wh = (unsigned short*)(gb + 256);        // 3*128*128 fp16
    // ---- zero zone (contiguous) ----
    int* deg       = (int*)(Wh + 3 * 128 * 128);             // 100000
    int* bucket_next = deg + N_NODES;                        // 8
    float* bnsums  = (float*)(bucket_next + NBUCK);          // 64*256
    // ---- end zero zone ----
    int* row_ptr   = (int*)(bnsums + BN_BANKS * 256);        // 100001
    int* nextp     = row_ptr + (N_NODES + 1);                // 100000
    int* partials  = nextp + N_NODES;                        // 128
    int* csr_src   = partials + 128;                         // 1.7M
    int2* buckets  = (int2*)(csr_src + M_TOT + 2);           // 8*240000 int2

    const int ZERO_CNT = N_NODES + NBUCK + BN_BANKS * 256;
    const int NB_EDGE = (M_TOT + EB_TPB - 1) / EB_TPB;       // 3321
    const int NB_PART = 2048;

    // ---- CSR build (bucketed, deg fused) + merged zero/W-convert ----
    zero_conv<<<(ZERO_CNT + 255) / 256, 256, 0, stream>>>(Wall, Wh, deg, ZERO_CNT);
    bucket_edges<<<NB_EDGE, EB_TPB, 0, stream>>>(ei, bucket_next, buckets, deg);
    block_sums<<<SCAN_NB, 256, 0, stream>>>(deg, partials);
    scan_partials<<<1, 128, 0, stream>>>(partials, SCAN_NB, row_ptr);
    scan_write<<<SCAN_NB, 256, 0, stream>>>(deg, partials, row_ptr, nextp);
    scatter_b<<<NB_PART, 256, 0, stream>>>(buckets, bucket_next, nextp, csr_src);

    // ---- 3 GAT layers (BN apply of layer l-1 fused into gemm of layer l;
    //      BN stats fused into aggregate; Y carried in fp16) ----
    for (int l = 0; l < 3; ++l) {
        const float* xf;
        const unsigned short* xh;
        const float* gbl;
        float* outw;
        if (l == 0) { xf = x; xh = nullptr; gbl = nullptr; outw = nullptr; }
        else        { xf = nullptr; xh = Yh; gbl = gb; outw = out + (size_t)(l - 1) * 128; }
        gemm_attn<<<(N_NODES + 63) / 64, 256, 0, stream>>>(
            xf, xh, Wh + (size_t)l * 128 * 128,
            asrcs + l * 128, adsts + l * 128, gbl, outw, Hh, Ssrc, Sdst);
        aggregate<<<N_NODES / 4, 256, 0, stream>>>(
            Hh, row_ptr, csr_src, Ssrc, Sdst, biases + l * 128, Yh, bnsums);
        bn_finalize<<<1, 256, 0, stream>>>(bnsums, gammas + l * 128,
                                           betas + l * 128, gb);
    }
    // final layer's BN apply (no following gemm to fuse into)
    bn_apply<<<(N_NODES * 16 + 255) / 256, 256, 0, stream>>>(
        Yh, gb, out + (size_t)2 * 128);
}